// Round 5
// baseline (385.779 us; speedup 1.0000x reference)
//
#include <hip/hip_runtime.h>

#define NVOX (64 * 64 * 64)          // 262144
#define FM (16 * NVOX)               // floats per mask field = 4,194,304 (16.8 MB)

// Mask encoding: 0 = pred-fg, 1 = target-fg, 2 = pred-bg, 3 = target-bg.
// seed (distance 0) = NOT-member of the mask (EDT measures distance to the
// nearest False voxel). Axis order Z -> Y -> X -> C; exact min-plus passes
// commute on ints ∪ {1e9} => bitwise-identical to reference (absmax 0.0 in
// rounds 2 and 4).

// ---------------------------------------------------------------------------
// Kernel 1: dice stats + CE + pred has_fg (unchanged from round 4).
// ---------------------------------------------------------------------------
__global__ __launch_bounds__(256, 4) void k_stats(const float* __restrict__ in,
                                                  const int* __restrict__ tg,
                                                  float* __restrict__ accF,
                                                  int* __restrict__ flags) {
    int tid0 = blockIdx.x * 256 + threadIdx.x;   // 0 .. 65535
    int lane = threadIdx.x & 63;
    int wid = threadIdx.x >> 6;
    __shared__ float part[4][25];
    __shared__ int af;

    for (int b = 0; b < 2; ++b) {
        float S1[8], S2[8], NN[8];
        float ce = 0.f;
        bool anyP = false;
#pragma unroll
        for (int c = 0; c < 8; ++c) { S1[c] = 0.f; S2[c] = 0.f; NN[c] = 0.f; }
        for (int ch = 0; ch < 4; ++ch) {
            int r = ch * 65536 + tid0;
            int t = tg[b * NVOX + r];
            float xs[8];
#pragma unroll
            for (int c = 0; c < 8; ++c) xs[c] = in[(b * 8 + c) * NVOX + r];
            float mx = xs[0];
#pragma unroll
            for (int c = 1; c < 8; ++c) mx = fmaxf(mx, xs[c]);
            float ex[8];
            float se = 0.f;
#pragma unroll
            for (int c = 0; c < 8; ++c) { ex[c] = expf(xs[c] - mx); se += ex[c]; }
            float inv = 1.f / se;
            float lse = mx + logf(se);
            float xt = xs[0];
#pragma unroll
            for (int c = 1; c < 8; ++c) xt = (t == c) ? xs[c] : xt;
            ce += lse - xt;
#pragma unroll
            for (int c = 0; c < 8; ++c) {
                float p = ex[c] * inv;
                S1[c] += p;
                S2[c] += (t == c) ? p : 0.f;
                NN[c] += (t == c) ? 1.f : 0.f;
                anyP = anyP || (xs[c] > 0.5f);
            }
        }
        float red[25];
#pragma unroll
        for (int c = 0; c < 8; ++c) {
            red[c] = S1[c]; red[8 + c] = S2[c]; red[16 + c] = NN[c];
        }
        red[24] = ce;
#pragma unroll
        for (int k = 0; k < 25; ++k) {
            float s = red[k];
            s += __shfl_down(s, 32);
            s += __shfl_down(s, 16);
            s += __shfl_down(s, 8);
            s += __shfl_down(s, 4);
            s += __shfl_down(s, 2);
            s += __shfl_down(s, 1);
            red[k] = s;
        }
        if (threadIdx.x == 0) af = 0;
        __syncthreads();
        bool wav = __any(anyP);
        if (lane == 0) {
#pragma unroll
            for (int k = 0; k < 25; ++k) part[wid][k] = red[k];
            if (wav) atomicOr(&af, 1);
        }
        __syncthreads();
        if (threadIdx.x < 25) {
            float s = part[0][threadIdx.x] + part[1][threadIdx.x] +
                      part[2][threadIdx.x] + part[3][threadIdx.x];
            atomicAdd(&accF[b * 25 + threadIdx.x], s);
        }
        if (threadIdx.x == 0 && af) atomicOr(&flags[b], 1);
        __syncthreads();
    }
}

// ===========================================================================
// FAST PATH
// ===========================================================================

// ---------------------------------------------------------------------------
// Kernel 2: all 4 masks per (b,c,x) slab. Wave m handles mask m; thread owns
// row y. Z-scan fully in registers (fwd[64], static indexing); single LDS
// write of d^2; then windowed Y min-plus from LDS, write f.
// ---------------------------------------------------------------------------
__global__ __launch_bounds__(256) void k_mask_zy4(const float* __restrict__ in,
                                                  const int* __restrict__ tg,
                                                  float* __restrict__ f) {
    __shared__ float tile[4 * 64 * 65];   // 66.56 KB
    int blk = blockIdx.x;                  // 0..1023
    int b = blk >> 9, c = (blk >> 6) & 7, x = blk & 63;
    int m = threadIdx.x >> 6;
    int y = threadIdx.x & 63;

    float fwd[64];
    float g = 1000.f;
    if ((m & 1) == 0) {                    // pred masks (m=0 fg, m=2 bg)
        const float4* src = (const float4*)(in + (b * 8 + c) * NVOX + x * 4096 + y * 64);
        bool inv = (m == 0);               // seed = fg XOR inv
#pragma unroll
        for (int q = 0; q < 16; ++q) {
            float4 v = src[q];
            bool s0 = (v.x > 0.5f) != inv;
            bool s1 = (v.y > 0.5f) != inv;
            bool s2 = (v.z > 0.5f) != inv;
            bool s3 = (v.w > 0.5f) != inv;
            g = s0 ? 0.f : g + 1.f; fwd[4 * q + 0] = g;
            g = s1 ? 0.f : g + 1.f; fwd[4 * q + 1] = g;
            g = s2 ? 0.f : g + 1.f; fwd[4 * q + 2] = g;
            g = s3 ? 0.f : g + 1.f; fwd[4 * q + 3] = g;
        }
    } else {                               // target masks (m=1 fg, m=3 bg)
        const int4* src = (const int4*)(tg + b * NVOX + x * 4096 + y * 64);
        bool inv = (m == 1);
#pragma unroll
        for (int q = 0; q < 16; ++q) {
            int4 v = src[q];
            bool s0 = (v.x == c) != inv;
            bool s1 = (v.y == c) != inv;
            bool s2 = (v.z == c) != inv;
            bool s3 = (v.w == c) != inv;
            g = s0 ? 0.f : g + 1.f; fwd[4 * q + 0] = g;
            g = s1 ? 0.f : g + 1.f; fwd[4 * q + 1] = g;
            g = s2 ? 0.f : g + 1.f; fwd[4 * q + 2] = g;
            g = s3 ? 0.f : g + 1.f; fwd[4 * q + 3] = g;
        }
    }
    // backward scan + d^2 into LDS row
    {
        float* trow = &tile[(m * 64 + y) * 65];
        float g2 = 1000.f;
#pragma unroll
        for (int z = 63; z >= 0; --z) {
            float gf = fwd[z];
            g2 = (gf == 0.f) ? 0.f : g2 + 1.f;
            float d = fminf(gf, g2);
            trow[z] = (d > 63.f) ? 1e9f : d * d;
        }
    }
    __syncthreads();

    // Y pass: thread owns column z of mask m; windowed exact min-plus.
    int z = threadIdx.x & 63;
    const float* tcol = &tile[m * 4160 + z];
    float* out = f + (size_t)m * FM + (b * 8 + c) * NVOX + x * 4096 + z;
    for (int i = 0; i < 64; ++i) {
        float d0 = tcol[i * 65];
        float d = d0;
        int Ri = (int)sqrtf(d0) + 1;
        Ri = (Ri > 63) ? 63 : Ri;
        for (int dd = 1; dd <= Ri; ++dd) {
            int jl = i - dd, jr = i + dd;
            float cl = (jl >= 0) ? tcol[jl * 65] : 1e9f;
            float cr = (jr < 64) ? tcol[jr * 65] : 1e9f;
            d = fminf(d, fminf(cl, cr) + (float)(dd * dd));
        }
        out[i * 64] = fminf(d, 1e9f);
    }
}

// ---------------------------------------------------------------------------
// Kernel 3: fused X pass + C-axis DT + HD reduction. Block = (b, y, 8-z
// chunk): 256 x-lines (4m x 8c x 8z) staged in LDS (stride 265 -> 2-way
// banks in both phases). X-DT in registers (column preserved -> exact),
// write back in-column, then per-voxel C min-plus + e^2 weighting.
// ---------------------------------------------------------------------------
__global__ __launch_bounds__(256) void k_xchd(const float* __restrict__ in,
                                              const int* __restrict__ tg,
                                              const float* __restrict__ f,
                                              const int* __restrict__ flags,
                                              double* __restrict__ partials) {
    __shared__ float wl[64 * 265];        // 67.84 KB
    __shared__ float part[4];
    int blk = blockIdx.x;                  // 0..1023
    int b = blk >> 9, y = (blk >> 3) & 63, zo = blk & 7;
    int lid = threadIdx.x;
    int m = lid >> 6, c = (lid >> 3) & 7, zi = lid & 7;

    // stage line (all x at fixed m,b,c,y,z) into LDS column lid
    const float* fb = f + (size_t)m * FM + (b * 8 + c) * NVOX + y * 64 + zo * 8 + zi;
#pragma unroll 4
    for (int xx = 0; xx < 64; ++xx) wl[xx * 265 + lid] = fb[(size_t)xx * 4096];

    // X windowed DT (buffer results in registers, fully static indexing)
    float d[64];
#pragma unroll
    for (int i = 0; i < 64; ++i) {
        float d0 = wl[i * 265 + lid];
        float dv = d0;
        int Ri = (int)sqrtf(d0) + 1;
        Ri = (Ri > 63) ? 63 : Ri;
        for (int dd = 1; dd <= Ri; ++dd) {
            int jl = i - dd, jr = i + dd;
            float cl = (jl >= 0) ? wl[jl * 265 + lid] : 1e9f;
            float cr = (jr < 64) ? wl[jr * 265 + lid] : 1e9f;
            dv = fminf(dv, fminf(cl, cr) + (float)(dd * dd));
        }
        d[i] = fminf(dv, 1e9f);
    }
#pragma unroll
    for (int i = 0; i < 64; ++i) wl[i * 265 + lid] = d[i];  // own column only
    __syncthreads();

    // C-axis DT + HD accumulate; lanes sweep x (2-way LDS banks).
    float fP = flags[b] ? 1.f : 0.f;
    float acc = 0.f;
#pragma unroll
    for (int k = 0; k < 2; ++k) {
        int vox = k * 256 + lid;
        int x = vox & 63;
        int zj = vox >> 6;                 // 0..7
        int idx3 = x * 4096 + y * 64 + zo * 8 + zj;
        int t = tg[b * NVOX + idx3];
        float e2[8];
#pragma unroll
        for (int cc = 0; cc < 8; ++cc) {
            float e = in[(b * 8 + cc) * NVOX + idx3] - ((t == cc) ? 1.f : 0.f);
            e2[cc] = e * e;
        }
#pragma unroll
        for (int mm = 0; mm < 4; ++mm) {
            float fl = (mm & 1) ? 1.f : fP;
            float fm[8];
#pragma unroll
            for (int cc = 0; cc < 8; ++cc)
                fm[cc] = wl[x * 265 + ((mm * 8 + cc) << 3) + zj];
            float am = 0.f;
#pragma unroll
            for (int i = 0; i < 8; ++i) {
                float dv = 1e9f;
#pragma unroll
                for (int j = 0; j < 8; ++j)
                    dv = fminf(dv, fm[j] + (float)((i - j) * (i - j)));
                am += e2[i] * dv;
            }
            acc += fl * am;
        }
    }
    acc += __shfl_down(acc, 32);
    acc += __shfl_down(acc, 16);
    acc += __shfl_down(acc, 8);
    acc += __shfl_down(acc, 4);
    acc += __shfl_down(acc, 2);
    acc += __shfl_down(acc, 1);
    int lane = threadIdx.x & 63;
    int wid = threadIdx.x >> 6;
    if (lane == 0) part[wid] = acc;
    __syncthreads();
    if (threadIdx.x == 0)
        partials[blk] = (double)(part[0] + part[1] + part[2] + part[3]);
}

// ---------------------------------------------------------------------------
// Kernel 4 (fast): reduce partials + assemble scalar loss.
// ---------------------------------------------------------------------------
__global__ __launch_bounds__(256) void k_final2(const float* __restrict__ accF,
                                                const double* __restrict__ partials,
                                                float* __restrict__ out) {
    __shared__ double ps[256];
    int tid = threadIdx.x;
    ps[tid] = partials[tid] + partials[tid + 256] +
              partials[tid + 512] + partials[tid + 768];
    __syncthreads();
    if (tid == 0) {
        double h = 0.0;
        for (int q = 0; q < 256; ++q) h += ps[q];
        float dsum = 0.f;
        for (int c = 1; c < 8; ++c) {
            float sc = 0.f;
            for (int b = 0; b < 2; ++b) {
                float S1 = accF[b * 25 + c];
                float S2 = accF[b * 25 + 8 + c];
                float Nc = accF[b * 25 + 16 + c];
                sc += 2.f * S2 / (2.f * S2 + (S1 - S2) + (Nc - S2) + 1e-5f);
            }
            dsum += sc * 0.5f;
        }
        float dice = 1.f - dsum / 7.f;
        float ce = (accF[24] + accF[25 + 24]) / 524288.f;
        out[0] = dice + ce + (float)(h / 4194304.0);
    }
}

// ===========================================================================
// FALLBACK PATH (small workspace) — round-4 kernels, verified absmax 0.0
// ===========================================================================
template <int M0>
__global__ __launch_bounds__(64) void k_mask_zy(const float* __restrict__ in,
                                                const int* __restrict__ tg,
                                                float* __restrict__ f) {
    __shared__ float tile[64 * 65];
    int blk = blockIdx.x;
    int m = M0 + (blk >> 10);
    int s = blk & 1023;
    int b = s >> 9, c = (s >> 6) & 7, x = s & 63;
    int tid = threadIdx.x;

    if ((m & 1) == 0) {
        const float* src = in + (b * 8 + c) * NVOX + x * 4096;
#pragma unroll 8
        for (int k = 0; k < 64; ++k) {
            bool fg = src[k * 64 + tid] > 0.5f;
            bool hot = (m < 2) ? fg : !fg;
            tile[k * 65 + tid] = hot ? 1e9f : 0.f;
        }
    } else {
        const int* src = tg + b * NVOX + x * 4096;
#pragma unroll 8
        for (int k = 0; k < 64; ++k) {
            bool fg = (src[k * 64 + tid] == c);
            bool hot = (m < 2) ? fg : !fg;
            tile[k * 65 + tid] = hot ? 1e9f : 0.f;
        }
    }
    __syncthreads();
    {
        float* row = &tile[tid * 65];
        float g = 1000.f;
#pragma unroll 8
        for (int z = 0; z < 64; ++z) {
            float v = row[z];
            g = (v == 0.f) ? 0.f : g + 1.f;
            row[z] = g;
        }
        g = 1000.f;
#pragma unroll 8
        for (int z = 63; z >= 0; --z) {
            float gf = row[z];
            g = (gf == 0.f) ? 0.f : g + 1.f;
            float d = fminf(gf, g);
            row[z] = (d > 63.f) ? 1e9f : d * d;
        }
    }
    __syncthreads();
    float* out = f + (size_t)(blk >> 10) * FM + (b * 8 + c) * NVOX + x * 4096;
    for (int i = 0; i < 64; ++i) {
        float d0 = tile[i * 65 + tid];
        float d = d0;
        int Ri = (int)sqrtf(d0) + 1;
        Ri = (Ri > 63) ? 63 : Ri;
        for (int dd = 1; dd <= Ri; ++dd) {
            float q = (float)(dd * dd);
            int jl = i - dd, jr = i + dd;
            float cl = (jl >= 0) ? tile[jl * 65 + tid] : 1e9f;
            float cr = (jr < 64) ? tile[jr * 65 + tid] : 1e9f;
            d = fminf(d, fminf(cl, cr) + q);
        }
        out[i * 64 + tid] = fminf(d, 1e9f);
    }
}

template <int M0>
__global__ __launch_bounds__(128, 4) void k_dtx(float* __restrict__ f) {
    __shared__ float wl[128 * 65];
    int blk = blockIdx.x;
    int mi = blk >> 9;
    int s = blk & 511;
    int plane = s >> 5;
    int y0 = (s & 31) * 2;
    int tid = threadIdx.x;
    float* fb = f + (size_t)mi * FM + plane * NVOX + y0 * 64;

#pragma unroll 8
    for (int j = 0; j < 64; ++j) wl[tid * 65 + j] = fb[j * 4096 + tid];

    float* row = &wl[tid * 65];
    for (int i = 0; i < 64; ++i) {
        float d0 = row[i];
        float d = d0;
        int Ri = (int)sqrtf(d0) + 1;
        Ri = (Ri > 63) ? 63 : Ri;
        for (int dd = 1; dd <= Ri; ++dd) {
            float q = (float)(dd * dd);
            int jl = i - dd, jr = i + dd;
            float cl = (jl >= 0) ? row[jl] : 1e9f;
            float cr = (jr < 64) ? row[jr] : 1e9f;
            d = fminf(d, fminf(cl, cr) + q);
        }
        fb[i * 4096 + tid] = fminf(d, 1e9f);
    }
}

template <int M0, int NM>
__global__ __launch_bounds__(256, 4) void k_cdt_hd(const float* __restrict__ in,
                                                   const int* __restrict__ tg,
                                                   const float* __restrict__ f,
                                                   const int* __restrict__ flags,
                                                   double* __restrict__ hd) {
    int v = blockIdx.x * 256 + threadIdx.x;
    int b = v >> 18;
    int r = v & (NVOX - 1);
    int t = tg[v];

    float e2[8];
#pragma unroll
    for (int c = 0; c < 8; ++c) {
        float e = in[(b * 8 + c) * NVOX + r] - ((t == c) ? 1.f : 0.f);
        e2[c] = e * e;
    }
    float acc = 0.f;
#pragma unroll
    for (int mi = 0; mi < NM; ++mi) {
        int m = M0 + mi;
        float fl = (m & 1) ? 1.f : (flags[b] ? 1.f : 0.f);
        float fm[8];
#pragma unroll
        for (int c = 0; c < 8; ++c)
            fm[c] = f[(size_t)mi * FM + (b * 8 + c) * NVOX + r];
        float am = 0.f;
#pragma unroll
        for (int i = 0; i < 8; ++i) {
            float d = 1e9f;
#pragma unroll
            for (int j = 0; j < 8; ++j)
                d = fminf(d, fm[j] + (float)((i - j) * (i - j)));
            am += e2[i] * d;
        }
        acc += fl * am;
    }
    float ssum = acc;
    ssum += __shfl_down(ssum, 32);
    ssum += __shfl_down(ssum, 16);
    ssum += __shfl_down(ssum, 8);
    ssum += __shfl_down(ssum, 4);
    ssum += __shfl_down(ssum, 2);
    ssum += __shfl_down(ssum, 1);
    __shared__ float part[4];
    int lane = threadIdx.x & 63;
    int wid = threadIdx.x >> 6;
    if (lane == 0) part[wid] = ssum;
    __syncthreads();
    if (threadIdx.x == 0)
        atomicAdd(hd, (double)(part[0] + part[1] + part[2] + part[3]));
}

__global__ void k_final(const float* __restrict__ accF,
                        const double* __restrict__ hd,
                        float* __restrict__ out) {
    float dsum = 0.f;
    for (int c = 1; c < 8; ++c) {
        float sc = 0.f;
        for (int b = 0; b < 2; ++b) {
            float S1 = accF[b * 25 + c];
            float S2 = accF[b * 25 + 8 + c];
            float Nc = accF[b * 25 + 16 + c];
            sc += 2.f * S2 / (2.f * S2 + (S1 - S2) + (Nc - S2) + 1e-5f);
        }
        dsum += sc * 0.5f;
    }
    float dice = 1.f - dsum / 7.f;
    float ce = (accF[24] + accF[25 + 24]) / 524288.f;
    float hdv = (float)(hd[0] / 4194304.0);
    out[0] = dice + ce + hdv;
}

template <int M0, int NM>
static void run_chunk(const float* in, const int* tg, float* f,
                      const int* flags, double* hd, hipStream_t stream) {
    k_mask_zy<M0><<<NM * 1024, 64, 0, stream>>>(in, tg, f);
    k_dtx<M0><<<NM * 512, 128, 0, stream>>>(f);
    k_cdt_hd<M0, NM><<<2048, 256, 0, stream>>>(in, tg, f, flags, hd);
}

// ---------------------------------------------------------------------------
extern "C" void kernel_launch(void* const* d_in, const int* in_sizes, int n_in,
                              void* d_out, int out_size, void* d_ws, size_t ws_size,
                              hipStream_t stream) {
    const float* in = (const float*)d_in[0];
    const int* tg = (const int*)d_in[1];
    float* out = (float*)d_out;

    size_t acc_off = ((ws_size - 256) / 256) * 256;
    char* accB = (char*)d_ws + acc_off;
    double* hd = (double*)accB;                    // @0
    float* accF = (float*)(accB + 8);              // @8  : float[2][25]
    int* flags = (int*)(accB + 208);               // @208: int[2]
    float* f = (float*)d_ws;

    hipMemsetAsync(accB, 0, 256, stream);
    k_stats<<<256, 256, 0, stream>>>(in, tg, accF, flags);

    size_t need_fast = (size_t)4 * FM * 4 + 1024 * sizeof(double);
    if (acc_off >= need_fast) {
        double* partials = (double*)((char*)d_ws + (size_t)4 * FM * 4);
        k_mask_zy4<<<1024, 256, 0, stream>>>(in, tg, f);
        k_xchd<<<1024, 256, 0, stream>>>(in, tg, f, flags, partials);
        k_final2<<<1, 256, 0, stream>>>(accF, partials, out);
    } else {
        int nm_cap = (int)(acc_off / ((size_t)FM * 4));
        if (nm_cap >= 2) {
            run_chunk<0, 2>(in, tg, f, flags, hd, stream);
            run_chunk<2, 2>(in, tg, f, flags, hd, stream);
        } else if (nm_cap >= 1) {
            run_chunk<0, 1>(in, tg, f, flags, hd, stream);
            run_chunk<1, 1>(in, tg, f, flags, hd, stream);
            run_chunk<2, 1>(in, tg, f, flags, hd, stream);
            run_chunk<3, 1>(in, tg, f, flags, hd, stream);
        }
        k_final<<<1, 1, 0, stream>>>(accF, hd, out);
    }
}

// Round 6
// 254.601 us; speedup vs baseline: 1.5152x; 1.5152x over previous
//
#include <hip/hip_runtime.h>

#define NVOX (64 * 64 * 64)          // 262144
#define FM (16 * NVOX)               // floats per mask field = 4,194,304 (16.8 MB)

// Mask encoding: 0 = pred-fg, 1 = target-fg, 2 = pred-bg, 3 = target-bg.
// seed (distance 0) = NOT-member of the mask. Axis order Z -> Y -> X -> C;
// exact min-plus passes commute on ints ∪ {1e9} => bitwise-identical to the
// reference (absmax 0.0 in rounds 2/4/5).

// ---------------------------------------------------------------------------
// Kernel 1: dice stats + CE + pred has_fg. 1024 blocks; thread <-> voxel r,
// loop over b. Coalesced channel reads; LDS cross-wave reduce.
// ---------------------------------------------------------------------------
__global__ __launch_bounds__(256, 4) void k_stats(const float* __restrict__ in,
                                                  const int* __restrict__ tg,
                                                  float* __restrict__ accF,
                                                  int* __restrict__ flags) {
    int r = blockIdx.x * 256 + threadIdx.x;      // 0 .. 262143
    int lane = threadIdx.x & 63;
    int wid = threadIdx.x >> 6;
    __shared__ float part[4][25];
    __shared__ int af;

    for (int b = 0; b < 2; ++b) {
        int t = tg[b * NVOX + r];
        float xs[8];
#pragma unroll
        for (int c = 0; c < 8; ++c) xs[c] = in[(b * 8 + c) * NVOX + r];
        float mx = xs[0];
#pragma unroll
        for (int c = 1; c < 8; ++c) mx = fmaxf(mx, xs[c]);
        float ex[8];
        float se = 0.f;
#pragma unroll
        for (int c = 0; c < 8; ++c) { ex[c] = expf(xs[c] - mx); se += ex[c]; }
        float inv = 1.f / se;
        float lse = mx + logf(se);
        float xt = xs[0];
#pragma unroll
        for (int c = 1; c < 8; ++c) xt = (t == c) ? xs[c] : xt;
        bool anyP = false;
        float red[25];
#pragma unroll
        for (int c = 0; c < 8; ++c) {
            float p = ex[c] * inv;
            red[c] = p;
            red[8 + c] = (t == c) ? p : 0.f;
            red[16 + c] = (t == c) ? 1.f : 0.f;
            anyP = anyP || (xs[c] > 0.5f);
        }
        red[24] = lse - xt;
#pragma unroll
        for (int k = 0; k < 25; ++k) {
            float s = red[k];
            s += __shfl_down(s, 32);
            s += __shfl_down(s, 16);
            s += __shfl_down(s, 8);
            s += __shfl_down(s, 4);
            s += __shfl_down(s, 2);
            s += __shfl_down(s, 1);
            red[k] = s;
        }
        if (threadIdx.x == 0) af = 0;
        __syncthreads();
        bool wav = __any(anyP);
        if (lane == 0) {
#pragma unroll
            for (int k = 0; k < 25; ++k) part[wid][k] = red[k];
            if (wav) atomicOr(&af, 1);
        }
        __syncthreads();
        if (threadIdx.x < 25) {
            float s = part[0][threadIdx.x] + part[1][threadIdx.x] +
                      part[2][threadIdx.x] + part[3][threadIdx.x];
            atomicAdd(&accF[b * 25 + threadIdx.x], s);
        }
        if (threadIdx.x == 0 && af) atomicOr(&flags[b], 1);
        __syncthreads();
    }
}

// ===========================================================================
// FAST PATH
// ===========================================================================

// ---------------------------------------------------------------------------
// Kernel 2: Z (ballot bit-trick, O(1)/voxel) + Y (windowed min-plus) for ONE
// mask per block. Block = (m,b,c,x) slab; 16.6 KB LDS -> 8 blocks/CU.
// Wave lanes <-> z; wave w handles rows y = 4k + w.
// ---------------------------------------------------------------------------
__global__ __launch_bounds__(256) void k_zy(const float* __restrict__ in,
                                            const int* __restrict__ tg,
                                            float* __restrict__ f) {
    __shared__ float tile[64 * 65];            // 16.64 KB
    int blk = blockIdx.x;                       // 0..4095
    int m = blk >> 10;
    int s = blk & 1023;
    int b = s >> 9, c = (s >> 6) & 7, x = s & 63;
    int w = threadIdx.x >> 6;                   // wave id 0..3
    int z = threadIdx.x & 63;                   // lane <-> z

    const float* pin = in + (b * 8 + c) * NVOX + x * 4096;
    const int* ptg = tg + b * NVOX + x * 4096;
    bool isPred = (m & 1) == 0;
    bool isFg = m < 2;

    float d0_reg[16];
#pragma unroll
    for (int k = 0; k < 16; ++k) {
        int y = k * 4 + w;
        bool member;
        if (isPred) member = pin[y * 64 + z] > 0.5f;
        else        member = ptg[y * 64 + z] == c;
        bool seed = isFg ? !member : member;
        unsigned long long mk = __ballot(seed);
        unsigned long long sf = mk << (63 - z);
        unsigned long long sb = mk >> z;
        int dfwd = sf ? __builtin_clzll(sf) : 64;
        int dbwd = sb ? __builtin_ctzll(sb) : 64;
        int d = dfwd < dbwd ? dfwd : dbwd;
        float d2 = (d > 63) ? 1e9f : (float)(d * d);
        tile[y * 65 + z] = d2;
        d0_reg[k] = d2;
    }
    __syncthreads();

    // Y windowed exact min-plus; Ri = floor(sqrt(d0))+1 > sqrt(d0).
    float* out = f + (size_t)m * FM + (b * 8 + c) * NVOX + x * 4096;
#pragma unroll
    for (int k = 0; k < 16; ++k) {
        int y = k * 4 + w;
        float d0 = d0_reg[k];
        float d = d0;
        int Ri = (d0 > 0.f) ? ((int)sqrtf(d0) + 1) : 0;
        Ri = (Ri > 63) ? 63 : Ri;
        for (int dd = 1; dd <= Ri; ++dd) {
            int jl = y - dd, jr = y + dd;
            float cl = (jl >= 0) ? tile[jl * 65 + z] : 1e9f;
            float cr = (jr < 64) ? tile[jr * 65 + z] : 1e9f;
            d = fminf(d, fminf(cl, cr) + (float)(dd * dd));
        }
        out[y * 64 + z] = fminf(d, 1e9f);
    }
}

// ---------------------------------------------------------------------------
// Kernel 3: X pass. Block = (m,b,c,y); stage [x][z] tile (coalesced, value
// kept in register), windowed min-plus over x, write back.
// ---------------------------------------------------------------------------
__global__ __launch_bounds__(256) void k_xdt(float* __restrict__ f) {
    __shared__ float tile[64 * 65];            // 16.64 KB
    int blk = blockIdx.x;                       // 0..4095
    int m = blk >> 10;
    int s = blk & 1023;
    int b = s >> 9, c = (s >> 6) & 7, y = s & 63;
    int w = threadIdx.x >> 6;
    int z = threadIdx.x & 63;

    float* base = f + (size_t)m * FM + (b * 8 + c) * NVOX + y * 64;

    float d0_reg[16];
#pragma unroll
    for (int k = 0; k < 16; ++k) {
        int x = k * 4 + w;
        float v = base[x * 4096 + z];
        tile[x * 65 + z] = v;
        d0_reg[k] = v;
    }
    __syncthreads();

#pragma unroll
    for (int k = 0; k < 16; ++k) {
        int x = k * 4 + w;
        float d0 = d0_reg[k];
        float d = d0;
        int Ri = (d0 > 0.f) ? ((int)sqrtf(d0) + 1) : 0;
        Ri = (Ri > 63) ? 63 : Ri;
        for (int dd = 1; dd <= Ri; ++dd) {
            int jl = x - dd, jr = x + dd;
            float cl = (jl >= 0) ? tile[jl * 65 + z] : 1e9f;
            float cr = (jr < 64) ? tile[jr * 65 + z] : 1e9f;
            d = fminf(d, fminf(cl, cr) + (float)(dd * dd));
        }
        base[x * 4096 + z] = fminf(d, 1e9f);
    }
}

// ---------------------------------------------------------------------------
// Kernel 4: C-axis (n=8) min-plus in registers + HD reduction. Pure
// streaming, no LDS tile, full occupancy. field^2 = f_fg + f_bg (cross term
// vanishes pointwise) => no sqrt.
// ---------------------------------------------------------------------------
__global__ __launch_bounds__(256, 4) void k_chd(const float* __restrict__ in,
                                                const int* __restrict__ tg,
                                                const float* __restrict__ f,
                                                const int* __restrict__ flags,
                                                double* __restrict__ partials) {
    int v = blockIdx.x * 256 + threadIdx.x;
    int b = v >> 18;
    int r = v & (NVOX - 1);
    int t = tg[v];

    float e2[8];
#pragma unroll
    for (int c = 0; c < 8; ++c) {
        float e = in[(b * 8 + c) * NVOX + r] - ((t == c) ? 1.f : 0.f);
        e2[c] = e * e;
    }
    float fP = flags[b] ? 1.f : 0.f;
    float acc = 0.f;
#pragma unroll
    for (int m = 0; m < 4; ++m) {
        float fl = (m & 1) ? 1.f : fP;
        float fm[8];
#pragma unroll
        for (int c = 0; c < 8; ++c)
            fm[c] = f[(size_t)m * FM + (b * 8 + c) * NVOX + r];
        float am = 0.f;
#pragma unroll
        for (int i = 0; i < 8; ++i) {
            float d = 1e9f;
#pragma unroll
            for (int j = 0; j < 8; ++j)
                d = fminf(d, fm[j] + (float)((i - j) * (i - j)));
            am += e2[i] * d;
        }
        acc += fl * am;
    }
    acc += __shfl_down(acc, 32);
    acc += __shfl_down(acc, 16);
    acc += __shfl_down(acc, 8);
    acc += __shfl_down(acc, 4);
    acc += __shfl_down(acc, 2);
    acc += __shfl_down(acc, 1);
    __shared__ float part[4];
    int lane = threadIdx.x & 63;
    int wid = threadIdx.x >> 6;
    if (lane == 0) part[wid] = acc;
    __syncthreads();
    if (threadIdx.x == 0)
        partials[blockIdx.x] = (double)(part[0] + part[1] + part[2] + part[3]);
}

// ---------------------------------------------------------------------------
// Kernel 5 (fast): reduce 2048 partials + assemble scalar loss.
// ---------------------------------------------------------------------------
__global__ __launch_bounds__(256) void k_final2(const float* __restrict__ accF,
                                                const double* __restrict__ partials,
                                                float* __restrict__ out) {
    __shared__ double ps[256];
    int tid = threadIdx.x;
    double s = 0.0;
#pragma unroll
    for (int q = 0; q < 8; ++q) s += partials[q * 256 + tid];
    ps[tid] = s;
    __syncthreads();
    if (tid == 0) {
        double h = 0.0;
        for (int q = 0; q < 256; ++q) h += ps[q];
        float dsum = 0.f;
        for (int c = 1; c < 8; ++c) {
            float sc = 0.f;
            for (int b = 0; b < 2; ++b) {
                float S1 = accF[b * 25 + c];
                float S2 = accF[b * 25 + 8 + c];
                float Nc = accF[b * 25 + 16 + c];
                sc += 2.f * S2 / (2.f * S2 + (S1 - S2) + (Nc - S2) + 1e-5f);
            }
            dsum += sc * 0.5f;
        }
        float dice = 1.f - dsum / 7.f;
        float ce = (accF[24] + accF[25 + 24]) / 524288.f;
        out[0] = dice + ce + (float)(h / 4194304.0);
    }
}

// ===========================================================================
// FALLBACK PATH (small workspace) — round-4 kernels, verified absmax 0.0
// ===========================================================================
template <int M0>
__global__ __launch_bounds__(64) void k_mask_zy(const float* __restrict__ in,
                                                const int* __restrict__ tg,
                                                float* __restrict__ f) {
    __shared__ float tile[64 * 65];
    int blk = blockIdx.x;
    int m = M0 + (blk >> 10);
    int s = blk & 1023;
    int b = s >> 9, c = (s >> 6) & 7, x = s & 63;
    int tid = threadIdx.x;

    if ((m & 1) == 0) {
        const float* src = in + (b * 8 + c) * NVOX + x * 4096;
#pragma unroll 8
        for (int k = 0; k < 64; ++k) {
            bool fg = src[k * 64 + tid] > 0.5f;
            bool hot = (m < 2) ? fg : !fg;
            tile[k * 65 + tid] = hot ? 1e9f : 0.f;
        }
    } else {
        const int* src = tg + b * NVOX + x * 4096;
#pragma unroll 8
        for (int k = 0; k < 64; ++k) {
            bool fg = (src[k * 64 + tid] == c);
            bool hot = (m < 2) ? fg : !fg;
            tile[k * 65 + tid] = hot ? 1e9f : 0.f;
        }
    }
    __syncthreads();
    {
        float* row = &tile[tid * 65];
        float g = 1000.f;
#pragma unroll 8
        for (int z = 0; z < 64; ++z) {
            float v = row[z];
            g = (v == 0.f) ? 0.f : g + 1.f;
            row[z] = g;
        }
        g = 1000.f;
#pragma unroll 8
        for (int z = 63; z >= 0; --z) {
            float gf = row[z];
            g = (gf == 0.f) ? 0.f : g + 1.f;
            float d = fminf(gf, g);
            row[z] = (d > 63.f) ? 1e9f : d * d;
        }
    }
    __syncthreads();
    float* out = f + (size_t)(blk >> 10) * FM + (b * 8 + c) * NVOX + x * 4096;
    for (int i = 0; i < 64; ++i) {
        float d0 = tile[i * 65 + tid];
        float d = d0;
        int Ri = (int)sqrtf(d0) + 1;
        Ri = (Ri > 63) ? 63 : Ri;
        for (int dd = 1; dd <= Ri; ++dd) {
            float q = (float)(dd * dd);
            int jl = i - dd, jr = i + dd;
            float cl = (jl >= 0) ? tile[jl * 65 + tid] : 1e9f;
            float cr = (jr < 64) ? tile[jr * 65 + tid] : 1e9f;
            d = fminf(d, fminf(cl, cr) + q);
        }
        out[i * 64 + tid] = fminf(d, 1e9f);
    }
}

template <int M0>
__global__ __launch_bounds__(128, 4) void k_dtx(float* __restrict__ f) {
    __shared__ float wl[128 * 65];
    int blk = blockIdx.x;
    int mi = blk >> 9;
    int s = blk & 511;
    int plane = s >> 5;
    int y0 = (s & 31) * 2;
    int tid = threadIdx.x;
    float* fb = f + (size_t)mi * FM + plane * NVOX + y0 * 64;

#pragma unroll 8
    for (int j = 0; j < 64; ++j) wl[tid * 65 + j] = fb[j * 4096 + tid];

    float* row = &wl[tid * 65];
    for (int i = 0; i < 64; ++i) {
        float d0 = row[i];
        float d = d0;
        int Ri = (int)sqrtf(d0) + 1;
        Ri = (Ri > 63) ? 63 : Ri;
        for (int dd = 1; dd <= Ri; ++dd) {
            float q = (float)(dd * dd);
            int jl = i - dd, jr = i + dd;
            float cl = (jl >= 0) ? row[jl] : 1e9f;
            float cr = (jr < 64) ? row[jr] : 1e9f;
            d = fminf(d, fminf(cl, cr) + q);
        }
        fb[i * 4096 + tid] = fminf(d, 1e9f);
    }
}

template <int M0, int NM>
__global__ __launch_bounds__(256, 4) void k_cdt_hd(const float* __restrict__ in,
                                                   const int* __restrict__ tg,
                                                   const float* __restrict__ f,
                                                   const int* __restrict__ flags,
                                                   double* __restrict__ hd) {
    int v = blockIdx.x * 256 + threadIdx.x;
    int b = v >> 18;
    int r = v & (NVOX - 1);
    int t = tg[v];

    float e2[8];
#pragma unroll
    for (int c = 0; c < 8; ++c) {
        float e = in[(b * 8 + c) * NVOX + r] - ((t == c) ? 1.f : 0.f);
        e2[c] = e * e;
    }
    float acc = 0.f;
#pragma unroll
    for (int mi = 0; mi < NM; ++mi) {
        int m = M0 + mi;
        float fl = (m & 1) ? 1.f : (flags[b] ? 1.f : 0.f);
        float fm[8];
#pragma unroll
        for (int c = 0; c < 8; ++c)
            fm[c] = f[(size_t)mi * FM + (b * 8 + c) * NVOX + r];
        float am = 0.f;
#pragma unroll
        for (int i = 0; i < 8; ++i) {
            float d = 1e9f;
#pragma unroll
            for (int j = 0; j < 8; ++j)
                d = fminf(d, fm[j] + (float)((i - j) * (i - j)));
            am += e2[i] * d;
        }
        acc += fl * am;
    }
    float ssum = acc;
    ssum += __shfl_down(ssum, 32);
    ssum += __shfl_down(ssum, 16);
    ssum += __shfl_down(ssum, 8);
    ssum += __shfl_down(ssum, 4);
    ssum += __shfl_down(ssum, 2);
    ssum += __shfl_down(ssum, 1);
    __shared__ float part[4];
    int lane = threadIdx.x & 63;
    int wid = threadIdx.x >> 6;
    if (lane == 0) part[wid] = ssum;
    __syncthreads();
    if (threadIdx.x == 0)
        atomicAdd(hd, (double)(part[0] + part[1] + part[2] + part[3]));
}

__global__ void k_final(const float* __restrict__ accF,
                        const double* __restrict__ hd,
                        float* __restrict__ out) {
    float dsum = 0.f;
    for (int c = 1; c < 8; ++c) {
        float sc = 0.f;
        for (int b = 0; b < 2; ++b) {
            float S1 = accF[b * 25 + c];
            float S2 = accF[b * 25 + 8 + c];
            float Nc = accF[b * 25 + 16 + c];
            sc += 2.f * S2 / (2.f * S2 + (S1 - S2) + (Nc - S2) + 1e-5f);
        }
        dsum += sc * 0.5f;
    }
    float dice = 1.f - dsum / 7.f;
    float ce = (accF[24] + accF[25 + 24]) / 524288.f;
    float hdv = (float)(hd[0] / 4194304.0);
    out[0] = dice + ce + hdv;
}

template <int M0, int NM>
static void run_chunk(const float* in, const int* tg, float* f,
                      const int* flags, double* hd, hipStream_t stream) {
    k_mask_zy<M0><<<NM * 1024, 64, 0, stream>>>(in, tg, f);
    k_dtx<M0><<<NM * 512, 128, 0, stream>>>(f);
    k_cdt_hd<M0, NM><<<2048, 256, 0, stream>>>(in, tg, f, flags, hd);
}

// ---------------------------------------------------------------------------
extern "C" void kernel_launch(void* const* d_in, const int* in_sizes, int n_in,
                              void* d_out, int out_size, void* d_ws, size_t ws_size,
                              hipStream_t stream) {
    const float* in = (const float*)d_in[0];
    const int* tg = (const int*)d_in[1];
    float* out = (float*)d_out;

    size_t acc_off = ((ws_size - 256) / 256) * 256;
    char* accB = (char*)d_ws + acc_off;
    double* hd = (double*)accB;                    // @0
    float* accF = (float*)(accB + 8);              // @8  : float[2][25]
    int* flags = (int*)(accB + 208);               // @208: int[2]
    float* f = (float*)d_ws;

    hipMemsetAsync(accB, 0, 256, stream);
    k_stats<<<1024, 256, 0, stream>>>(in, tg, accF, flags);

    size_t need_fast = (size_t)4 * FM * 4 + 2048 * sizeof(double);
    if (acc_off >= need_fast) {
        double* partials = (double*)((char*)d_ws + (size_t)4 * FM * 4);
        k_zy<<<4096, 256, 0, stream>>>(in, tg, f);
        k_xdt<<<4096, 256, 0, stream>>>(f);
        k_chd<<<2048, 256, 0, stream>>>(in, tg, f, flags, partials);
        k_final2<<<1, 256, 0, stream>>>(accF, partials, out);
    } else {
        int nm_cap = (int)(acc_off / ((size_t)FM * 4));
        if (nm_cap >= 2) {
            run_chunk<0, 2>(in, tg, f, flags, hd, stream);
            run_chunk<2, 2>(in, tg, f, flags, hd, stream);
        } else if (nm_cap >= 1) {
            run_chunk<0, 1>(in, tg, f, flags, hd, stream);
            run_chunk<1, 1>(in, tg, f, flags, hd, stream);
            run_chunk<2, 1>(in, tg, f, flags, hd, stream);
            run_chunk<3, 1>(in, tg, f, flags, hd, stream);
        }
        k_final<<<1, 1, 0, stream>>>(accF, hd, out);
    }
}

// Round 7
// 189.368 us; speedup vs baseline: 2.0372x; 1.3445x over previous
//
#include <hip/hip_runtime.h>

#define NVOX (64 * 64 * 64)          // 262144
#define FM (16 * NVOX)               // floats per mask field = 4,194,304 (16.8 MB)

// Mask encoding: 0 = pred-fg, 1 = target-fg, 2 = pred-bg, 3 = target-bg.
// seed (distance 0) = NOT-member of the mask. Axis order Z -> Y -> X -> C;
// exact min-plus passes commute on ints ∪ {1e9} => bitwise-identical to the
// reference (absmax 0.0 in rounds 2/4/5/6).
//
// Window loops use a DYNAMIC break: once dd^2 >= d_current, every remaining
// candidate (>= dd^2, since LDS values >= 0) cannot improve the min => exact,
// and strictly tighter than the static Ri = sqrt(d0)+1 bound.

// ---------------------------------------------------------------------------
// Kernel 1: dice stats + CE + pred has_fg. Thread <-> voxel r, loop over b.
// ---------------------------------------------------------------------------
__global__ __launch_bounds__(256, 4) void k_stats(const float* __restrict__ in,
                                                  const int* __restrict__ tg,
                                                  float* __restrict__ accF,
                                                  int* __restrict__ flags) {
    int r = blockIdx.x * 256 + threadIdx.x;      // 0 .. 262143
    int lane = threadIdx.x & 63;
    int wid = threadIdx.x >> 6;
    __shared__ float part[4][25];
    __shared__ int af;

    for (int b = 0; b < 2; ++b) {
        int t = tg[b * NVOX + r];
        float xs[8];
#pragma unroll
        for (int c = 0; c < 8; ++c) xs[c] = in[(b * 8 + c) * NVOX + r];
        float mx = xs[0];
#pragma unroll
        for (int c = 1; c < 8; ++c) mx = fmaxf(mx, xs[c]);
        float ex[8];
        float se = 0.f;
#pragma unroll
        for (int c = 0; c < 8; ++c) { ex[c] = expf(xs[c] - mx); se += ex[c]; }
        float inv = 1.f / se;
        float lse = mx + logf(se);
        float xt = xs[0];
#pragma unroll
        for (int c = 1; c < 8; ++c) xt = (t == c) ? xs[c] : xt;
        bool anyP = false;
        float red[25];
#pragma unroll
        for (int c = 0; c < 8; ++c) {
            float p = ex[c] * inv;
            red[c] = p;
            red[8 + c] = (t == c) ? p : 0.f;
            red[16 + c] = (t == c) ? 1.f : 0.f;
            anyP = anyP || (xs[c] > 0.5f);
        }
        red[24] = lse - xt;
#pragma unroll
        for (int k = 0; k < 25; ++k) {
            float s = red[k];
            s += __shfl_down(s, 32);
            s += __shfl_down(s, 16);
            s += __shfl_down(s, 8);
            s += __shfl_down(s, 4);
            s += __shfl_down(s, 2);
            s += __shfl_down(s, 1);
            red[k] = s;
        }
        if (threadIdx.x == 0) af = 0;
        __syncthreads();
        bool wav = __any(anyP);
        if (lane == 0) {
#pragma unroll
            for (int k = 0; k < 25; ++k) part[wid][k] = red[k];
            if (wav) atomicOr(&af, 1);
        }
        __syncthreads();
        if (threadIdx.x < 25) {
            float s = part[0][threadIdx.x] + part[1][threadIdx.x] +
                      part[2][threadIdx.x] + part[3][threadIdx.x];
            atomicAdd(&accF[b * 25 + threadIdx.x], s);
        }
        if (threadIdx.x == 0 && af) atomicOr(&flags[b], 1);
        __syncthreads();
    }
}

// ===========================================================================
// FAST PATH
// ===========================================================================

// ---------------------------------------------------------------------------
// Kernel 2: Z (ballot bit-trick, O(1)/voxel) + Y (dynamic-break min-plus).
// Block = (m,b,c,x) slab; 16.6 KB LDS. Wave lanes <-> z; wave w: y = 4k+w.
// ---------------------------------------------------------------------------
__global__ __launch_bounds__(256) void k_zy(const float* __restrict__ in,
                                            const int* __restrict__ tg,
                                            float* __restrict__ f) {
    __shared__ float tile[64 * 65];            // 16.64 KB
    int blk = blockIdx.x;                       // 0..4095
    int m = blk >> 10;
    int s = blk & 1023;
    int b = s >> 9, c = (s >> 6) & 7, x = s & 63;
    int w = threadIdx.x >> 6;                   // wave id 0..3
    int z = threadIdx.x & 63;                   // lane <-> z

    const float* pin = in + (b * 8 + c) * NVOX + x * 4096;
    const int* ptg = tg + b * NVOX + x * 4096;
    bool isPred = (m & 1) == 0;
    bool isFg = m < 2;

    float d0_reg[16];
#pragma unroll
    for (int k = 0; k < 16; ++k) {
        int y = k * 4 + w;
        bool member;
        if (isPred) member = pin[y * 64 + z] > 0.5f;
        else        member = ptg[y * 64 + z] == c;
        bool seed = isFg ? !member : member;
        unsigned long long mk = __ballot(seed);
        unsigned long long sf = mk << (63 - z);
        unsigned long long sb = mk >> z;
        int dfwd = sf ? __builtin_clzll(sf) : 64;
        int dbwd = sb ? __builtin_ctzll(sb) : 64;
        int d = dfwd < dbwd ? dfwd : dbwd;
        float d2 = (d > 63) ? 1e9f : (float)(d * d);
        tile[y * 65 + z] = d2;
        d0_reg[k] = d2;
    }
    __syncthreads();

    // Y min-plus with dynamic break (exact).
    float* out = f + (size_t)m * FM + (b * 8 + c) * NVOX + x * 4096;
#pragma unroll
    for (int k = 0; k < 16; ++k) {
        int y = k * 4 + w;
        float d = d0_reg[k];
        int q = 1;                               // dd*dd
        for (int dd = 1; dd <= 63 && (float)q < d; ++dd) {
            int jl = y - dd, jr = y + dd;
            float cl = (jl >= 0) ? tile[jl * 65 + z] : 1e9f;
            float cr = (jr < 64) ? tile[jr * 65 + z] : 1e9f;
            d = fminf(d, fminf(cl, cr) + (float)q);
            q += 2 * dd + 1;
        }
        out[y * 64 + z] = fminf(d, 1e9f);
    }
}

// ---------------------------------------------------------------------------
// Kernel 3: X pass with dynamic break. Block = (m,b,c,y); lane <-> z.
// ---------------------------------------------------------------------------
__global__ __launch_bounds__(256) void k_xdt(float* __restrict__ f) {
    __shared__ float tile[64 * 65];            // 16.64 KB
    int blk = blockIdx.x;                       // 0..4095
    int m = blk >> 10;
    int s = blk & 1023;
    int b = s >> 9, c = (s >> 6) & 7, y = s & 63;
    int w = threadIdx.x >> 6;
    int z = threadIdx.x & 63;

    float* base = f + (size_t)m * FM + (b * 8 + c) * NVOX + y * 64;

    float d0_reg[16];
#pragma unroll
    for (int k = 0; k < 16; ++k) {
        int x = k * 4 + w;
        float v = base[x * 4096 + z];
        tile[x * 65 + z] = v;
        d0_reg[k] = v;
    }
    __syncthreads();

#pragma unroll
    for (int k = 0; k < 16; ++k) {
        int x = k * 4 + w;
        float d = d0_reg[k];
        int q = 1;
        for (int dd = 1; dd <= 63 && (float)q < d; ++dd) {
            int jl = x - dd, jr = x + dd;
            float cl = (jl >= 0) ? tile[jl * 65 + z] : 1e9f;
            float cr = (jr < 64) ? tile[jr * 65 + z] : 1e9f;
            d = fminf(d, fminf(cl, cr) + (float)q);
            q += 2 * dd + 1;
        }
        base[x * 4096 + z] = fminf(d, 1e9f);
    }
}

// ---------------------------------------------------------------------------
// Kernel 4: C-axis (n=8) min-plus in registers + HD reduction (streaming).
// field^2 = f_fg + f_bg (cross term vanishes pointwise) => no sqrt.
// ---------------------------------------------------------------------------
__global__ __launch_bounds__(256, 4) void k_chd(const float* __restrict__ in,
                                                const int* __restrict__ tg,
                                                const float* __restrict__ f,
                                                const int* __restrict__ flags,
                                                double* __restrict__ partials) {
    int v = blockIdx.x * 256 + threadIdx.x;
    int b = v >> 18;
    int r = v & (NVOX - 1);
    int t = tg[v];

    float e2[8];
#pragma unroll
    for (int c = 0; c < 8; ++c) {
        float e = in[(b * 8 + c) * NVOX + r] - ((t == c) ? 1.f : 0.f);
        e2[c] = e * e;
    }
    float fP = flags[b] ? 1.f : 0.f;
    float acc = 0.f;
#pragma unroll
    for (int m = 0; m < 4; ++m) {
        float fl = (m & 1) ? 1.f : fP;
        float fm[8];
#pragma unroll
        for (int c = 0; c < 8; ++c)
            fm[c] = f[(size_t)m * FM + (b * 8 + c) * NVOX + r];
        float am = 0.f;
#pragma unroll
        for (int i = 0; i < 8; ++i) {
            float d = 1e9f;
#pragma unroll
            for (int j = 0; j < 8; ++j)
                d = fminf(d, fm[j] + (float)((i - j) * (i - j)));
            am += e2[i] * d;
        }
        acc += fl * am;
    }
    acc += __shfl_down(acc, 32);
    acc += __shfl_down(acc, 16);
    acc += __shfl_down(acc, 8);
    acc += __shfl_down(acc, 4);
    acc += __shfl_down(acc, 2);
    acc += __shfl_down(acc, 1);
    __shared__ float part[4];
    int lane = threadIdx.x & 63;
    int wid = threadIdx.x >> 6;
    if (lane == 0) part[wid] = acc;
    __syncthreads();
    if (threadIdx.x == 0)
        partials[blockIdx.x] = (double)(part[0] + part[1] + part[2] + part[3]);
}

// ---------------------------------------------------------------------------
// Kernel 5 (fast): reduce 2048 partials + assemble scalar loss.
// ---------------------------------------------------------------------------
__global__ __launch_bounds__(256) void k_final2(const float* __restrict__ accF,
                                                const double* __restrict__ partials,
                                                float* __restrict__ out) {
    __shared__ double ps[256];
    int tid = threadIdx.x;
    double s = 0.0;
#pragma unroll
    for (int q = 0; q < 8; ++q) s += partials[q * 256 + tid];
    ps[tid] = s;
    __syncthreads();
    if (tid == 0) {
        double h = 0.0;
        for (int q = 0; q < 256; ++q) h += ps[q];
        float dsum = 0.f;
        for (int c = 1; c < 8; ++c) {
            float sc = 0.f;
            for (int b = 0; b < 2; ++b) {
                float S1 = accF[b * 25 + c];
                float S2 = accF[b * 25 + 8 + c];
                float Nc = accF[b * 25 + 16 + c];
                sc += 2.f * S2 / (2.f * S2 + (S1 - S2) + (Nc - S2) + 1e-5f);
            }
            dsum += sc * 0.5f;
        }
        float dice = 1.f - dsum / 7.f;
        float ce = (accF[24] + accF[25 + 24]) / 524288.f;
        out[0] = dice + ce + (float)(h / 4194304.0);
    }
}

// ===========================================================================
// FALLBACK PATH (small workspace) — round-4 kernels, verified absmax 0.0
// ===========================================================================
template <int M0>
__global__ __launch_bounds__(64) void k_mask_zy(const float* __restrict__ in,
                                                const int* __restrict__ tg,
                                                float* __restrict__ f) {
    __shared__ float tile[64 * 65];
    int blk = blockIdx.x;
    int m = M0 + (blk >> 10);
    int s = blk & 1023;
    int b = s >> 9, c = (s >> 6) & 7, x = s & 63;
    int tid = threadIdx.x;

    if ((m & 1) == 0) {
        const float* src = in + (b * 8 + c) * NVOX + x * 4096;
#pragma unroll 8
        for (int k = 0; k < 64; ++k) {
            bool fg = src[k * 64 + tid] > 0.5f;
            bool hot = (m < 2) ? fg : !fg;
            tile[k * 65 + tid] = hot ? 1e9f : 0.f;
        }
    } else {
        const int* src = tg + b * NVOX + x * 4096;
#pragma unroll 8
        for (int k = 0; k < 64; ++k) {
            bool fg = (src[k * 64 + tid] == c);
            bool hot = (m < 2) ? fg : !fg;
            tile[k * 65 + tid] = hot ? 1e9f : 0.f;
        }
    }
    __syncthreads();
    {
        float* row = &tile[tid * 65];
        float g = 1000.f;
#pragma unroll 8
        for (int z = 0; z < 64; ++z) {
            float v = row[z];
            g = (v == 0.f) ? 0.f : g + 1.f;
            row[z] = g;
        }
        g = 1000.f;
#pragma unroll 8
        for (int z = 63; z >= 0; --z) {
            float gf = row[z];
            g = (gf == 0.f) ? 0.f : g + 1.f;
            float d = fminf(gf, g);
            row[z] = (d > 63.f) ? 1e9f : d * d;
        }
    }
    __syncthreads();
    float* out = f + (size_t)(blk >> 10) * FM + (b * 8 + c) * NVOX + x * 4096;
    for (int i = 0; i < 64; ++i) {
        float d0 = tile[i * 65 + tid];
        float d = d0;
        int Ri = (int)sqrtf(d0) + 1;
        Ri = (Ri > 63) ? 63 : Ri;
        for (int dd = 1; dd <= Ri; ++dd) {
            float q = (float)(dd * dd);
            int jl = i - dd, jr = i + dd;
            float cl = (jl >= 0) ? tile[jl * 65 + tid] : 1e9f;
            float cr = (jr < 64) ? tile[jr * 65 + tid] : 1e9f;
            d = fminf(d, fminf(cl, cr) + q);
        }
        out[i * 64 + tid] = fminf(d, 1e9f);
    }
}

template <int M0>
__global__ __launch_bounds__(128, 4) void k_dtx(float* __restrict__ f) {
    __shared__ float wl[128 * 65];
    int blk = blockIdx.x;
    int mi = blk >> 9;
    int s = blk & 511;
    int plane = s >> 5;
    int y0 = (s & 31) * 2;
    int tid = threadIdx.x;
    float* fb = f + (size_t)mi * FM + plane * NVOX + y0 * 64;

#pragma unroll 8
    for (int j = 0; j < 64; ++j) wl[tid * 65 + j] = fb[j * 4096 + tid];

    float* row = &wl[tid * 65];
    for (int i = 0; i < 64; ++i) {
        float d0 = row[i];
        float d = d0;
        int Ri = (int)sqrtf(d0) + 1;
        Ri = (Ri > 63) ? 63 : Ri;
        for (int dd = 1; dd <= Ri; ++dd) {
            float q = (float)(dd * dd);
            int jl = i - dd, jr = i + dd;
            float cl = (jl >= 0) ? row[jl] : 1e9f;
            float cr = (jr < 64) ? row[jr] : 1e9f;
            d = fminf(d, fminf(cl, cr) + q);
        }
        fb[i * 4096 + tid] = fminf(d, 1e9f);
    }
}

template <int M0, int NM>
__global__ __launch_bounds__(256, 4) void k_cdt_hd(const float* __restrict__ in,
                                                   const int* __restrict__ tg,
                                                   const float* __restrict__ f,
                                                   const int* __restrict__ flags,
                                                   double* __restrict__ hd) {
    int v = blockIdx.x * 256 + threadIdx.x;
    int b = v >> 18;
    int r = v & (NVOX - 1);
    int t = tg[v];

    float e2[8];
#pragma unroll
    for (int c = 0; c < 8; ++c) {
        float e = in[(b * 8 + c) * NVOX + r] - ((t == c) ? 1.f : 0.f);
        e2[c] = e * e;
    }
    float acc = 0.f;
#pragma unroll
    for (int mi = 0; mi < NM; ++mi) {
        int m = M0 + mi;
        float fl = (m & 1) ? 1.f : (flags[b] ? 1.f : 0.f);
        float fm[8];
#pragma unroll
        for (int c = 0; c < 8; ++c)
            fm[c] = f[(size_t)mi * FM + (b * 8 + c) * NVOX + r];
        float am = 0.f;
#pragma unroll
        for (int i = 0; i < 8; ++i) {
            float d = 1e9f;
#pragma unroll
            for (int j = 0; j < 8; ++j)
                d = fminf(d, fm[j] + (float)((i - j) * (i - j)));
            am += e2[i] * d;
        }
        acc += fl * am;
    }
    float ssum = acc;
    ssum += __shfl_down(ssum, 32);
    ssum += __shfl_down(ssum, 16);
    ssum += __shfl_down(ssum, 8);
    ssum += __shfl_down(ssum, 4);
    ssum += __shfl_down(ssum, 2);
    ssum += __shfl_down(ssum, 1);
    __shared__ float part[4];
    int lane = threadIdx.x & 63;
    int wid = threadIdx.x >> 6;
    if (lane == 0) part[wid] = ssum;
    __syncthreads();
    if (threadIdx.x == 0)
        atomicAdd(hd, (double)(part[0] + part[1] + part[2] + part[3]));
}

__global__ void k_final(const float* __restrict__ accF,
                        const double* __restrict__ hd,
                        float* __restrict__ out) {
    float dsum = 0.f;
    for (int c = 1; c < 8; ++c) {
        float sc = 0.f;
        for (int b = 0; b < 2; ++b) {
            float S1 = accF[b * 25 + c];
            float S2 = accF[b * 25 + 8 + c];
            float Nc = accF[b * 25 + 16 + c];
            sc += 2.f * S2 / (2.f * S2 + (S1 - S2) + (Nc - S2) + 1e-5f);
        }
        dsum += sc * 0.5f;
    }
    float dice = 1.f - dsum / 7.f;
    float ce = (accF[24] + accF[25 + 24]) / 524288.f;
    float hdv = (float)(hd[0] / 4194304.0);
    out[0] = dice + ce + hdv;
}

template <int M0, int NM>
static void run_chunk(const float* in, const int* tg, float* f,
                      const int* flags, double* hd, hipStream_t stream) {
    k_mask_zy<M0><<<NM * 1024, 64, 0, stream>>>(in, tg, f);
    k_dtx<M0><<<NM * 512, 128, 0, stream>>>(f);
    k_cdt_hd<M0, NM><<<2048, 256, 0, stream>>>(in, tg, f, flags, hd);
}

// ---------------------------------------------------------------------------
extern "C" void kernel_launch(void* const* d_in, const int* in_sizes, int n_in,
                              void* d_out, int out_size, void* d_ws, size_t ws_size,
                              hipStream_t stream) {
    const float* in = (const float*)d_in[0];
    const int* tg = (const int*)d_in[1];
    float* out = (float*)d_out;

    size_t acc_off = ((ws_size - 256) / 256) * 256;
    char* accB = (char*)d_ws + acc_off;
    double* hd = (double*)accB;                    // @0
    float* accF = (float*)(accB + 8);              // @8  : float[2][25]
    int* flags = (int*)(accB + 208);               // @208: int[2]
    float* f = (float*)d_ws;

    hipMemsetAsync(accB, 0, 256, stream);
    k_stats<<<1024, 256, 0, stream>>>(in, tg, accF, flags);

    size_t need_fast = (size_t)4 * FM * 4 + 2048 * sizeof(double);
    if (acc_off >= need_fast) {
        double* partials = (double*)((char*)d_ws + (size_t)4 * FM * 4);
        k_zy<<<4096, 256, 0, stream>>>(in, tg, f);
        k_xdt<<<4096, 256, 0, stream>>>(f);
        k_chd<<<2048, 256, 0, stream>>>(in, tg, f, flags, partials);
        k_final2<<<1, 256, 0, stream>>>(accF, partials, out);
    } else {
        int nm_cap = (int)(acc_off / ((size_t)FM * 4));
        if (nm_cap >= 2) {
            run_chunk<0, 2>(in, tg, f, flags, hd, stream);
            run_chunk<2, 2>(in, tg, f, flags, hd, stream);
        } else if (nm_cap >= 1) {
            run_chunk<0, 1>(in, tg, f, flags, hd, stream);
            run_chunk<1, 1>(in, tg, f, flags, hd, stream);
            run_chunk<2, 1>(in, tg, f, flags, hd, stream);
            run_chunk<3, 1>(in, tg, f, flags, hd, stream);
        }
        k_final<<<1, 1, 0, stream>>>(accF, hd, out);
    }
}

// Round 8
// 150.799 us; speedup vs baseline: 2.5582x; 1.2558x over previous
//
#include <hip/hip_runtime.h>

#define NVOX (64 * 64 * 64)          // 262144
#define FM (16 * NVOX)               // floats per mask field = 4,194,304 (16.8 MB)

// Mask encoding: 0 = pred-fg, 1 = target-fg, 2 = pred-bg, 3 = target-bg.
// seed (distance 0) = NOT-member of the mask. Axis order Z -> Y -> X -> C;
// exact min-plus passes commute on ints ∪ {1e9} => bitwise-identical to the
// reference (absmax 0.0 in rounds 2/4/5/6/7).
//
// Window loops use a DYNAMIC break: once dd^2 >= d_current, remaining
// candidates (>= dd^2) cannot improve the min => exact.

// ===========================================================================
// FAST PATH
// ===========================================================================

// ---------------------------------------------------------------------------
// Kernel 1: Z (one ballot gives BOTH fg and bg masks: complements) +
// Y (dynamic-break min-plus) for a (src,b,c,x) slab. src 0 = pred, 1 = target.
// Writes masks m=src (fg) and m=src+2 (bg).
// ---------------------------------------------------------------------------
__global__ __launch_bounds__(256) void k_zy2(const float* __restrict__ in,
                                             const int* __restrict__ tg,
                                             float* __restrict__ f) {
    __shared__ float tA[64 * 65];              // fg distances (16.64 KB)
    __shared__ float tB[64 * 65];              // bg distances
    int blk = blockIdx.x;                       // 0..2047
    int src = blk >> 10;
    int s = blk & 1023;
    int b = s >> 9, c = (s >> 6) & 7, x = s & 63;
    int w = threadIdx.x >> 6;                   // wave 0..3
    int z = threadIdx.x & 63;                   // lane <-> z

    const float* pin = in + (b * 8 + c) * NVOX + x * 4096;
    const int* ptg = tg + b * NVOX + x * 4096;

    float dA[16], dB[16];
#pragma unroll
    for (int k = 0; k < 16; ++k) {
        int y = k * 4 + w;
        bool member;
        if (src == 0) member = pin[y * 64 + z] > 0.5f;
        else          member = ptg[y * 64 + z] == c;
        unsigned long long mkA = __ballot(!member);   // fg seeds = non-members
        unsigned long long mkB = ~mkA;                // bg seeds = members
        unsigned long long sfA = mkA << (63 - z), sbA = mkA >> z;
        int dfA = sfA ? __builtin_clzll(sfA) : 64;
        int dbA = sbA ? __builtin_ctzll(sbA) : 64;
        int da = dfA < dbA ? dfA : dbA;
        unsigned long long sfB = mkB << (63 - z), sbB = mkB >> z;
        int dfB = sfB ? __builtin_clzll(sfB) : 64;
        int dbB = sbB ? __builtin_ctzll(sbB) : 64;
        int db = dfB < dbB ? dfB : dbB;
        float a2 = (da > 63) ? 1e9f : (float)(da * da);
        float b2 = (db > 63) ? 1e9f : (float)(db * db);
        tA[y * 65 + z] = a2;
        tB[y * 65 + z] = b2;
        dA[k] = a2;
        dB[k] = b2;
    }
    __syncthreads();

    float* outA = f + (size_t)src * FM + (b * 8 + c) * NVOX + x * 4096;
    float* outB = f + (size_t)(src + 2) * FM + (b * 8 + c) * NVOX + x * 4096;
#pragma unroll
    for (int k = 0; k < 16; ++k) {
        int y = k * 4 + w;
        float d = dA[k];
        int q = 1;
        for (int dd = 1; dd <= 63 && (float)q < d; ++dd) {
            int jl = y - dd, jr = y + dd;
            float cl = (jl >= 0) ? tA[jl * 65 + z] : 1e9f;
            float cr = (jr < 64) ? tA[jr * 65 + z] : 1e9f;
            d = fminf(d, fminf(cl, cr) + (float)q);
            q += 2 * dd + 1;
        }
        outA[y * 64 + z] = fminf(d, 1e9f);
    }
#pragma unroll
    for (int k = 0; k < 16; ++k) {
        int y = k * 4 + w;
        float d = dB[k];
        int q = 1;
        for (int dd = 1; dd <= 63 && (float)q < d; ++dd) {
            int jl = y - dd, jr = y + dd;
            float cl = (jl >= 0) ? tB[jl * 65 + z] : 1e9f;
            float cr = (jr < 64) ? tB[jr * 65 + z] : 1e9f;
            d = fminf(d, fminf(cl, cr) + (float)q);
            q += 2 * dd + 1;
        }
        outB[y * 64 + z] = fminf(d, 1e9f);
    }
}

// ---------------------------------------------------------------------------
// Kernel 2: X pass with dynamic break. Block = (m,b,c,y); lane <-> z.
// ---------------------------------------------------------------------------
__global__ __launch_bounds__(256) void k_xdt(float* __restrict__ f) {
    __shared__ float tile[64 * 65];            // 16.64 KB
    int blk = blockIdx.x;                       // 0..4095
    int m = blk >> 10;
    int s = blk & 1023;
    int b = s >> 9, c = (s >> 6) & 7, y = s & 63;
    int w = threadIdx.x >> 6;
    int z = threadIdx.x & 63;

    float* base = f + (size_t)m * FM + (b * 8 + c) * NVOX + y * 64;

    float d0_reg[16];
#pragma unroll
    for (int k = 0; k < 16; ++k) {
        int x = k * 4 + w;
        float v = base[x * 4096 + z];
        tile[x * 65 + z] = v;
        d0_reg[k] = v;
    }
    __syncthreads();

#pragma unroll
    for (int k = 0; k < 16; ++k) {
        int x = k * 4 + w;
        float d = d0_reg[k];
        int q = 1;
        for (int dd = 1; dd <= 63 && (float)q < d; ++dd) {
            int jl = x - dd, jr = x + dd;
            float cl = (jl >= 0) ? tile[jl * 65 + z] : 1e9f;
            float cr = (jr < 64) ? tile[jr * 65 + z] : 1e9f;
            d = fminf(d, fminf(cl, cr) + (float)q);
            q += 2 * dd + 1;
        }
        base[x * 4096 + z] = fminf(d, 1e9f);
    }
}

// ---------------------------------------------------------------------------
// Kernel 3: fused C-axis DT + HD + softmax stats + CE + pred-has-fg.
// Per-block partials (block-owned slots -> ZERO atomic contention).
// Pred/target HD sums kept separate so the has_fg flag can be applied at
// final time. field^2 = f_fg + f_bg pointwise => no sqrt.
// statP layout: [(b*26 + q)*1024 + j], q: 0-7 S1, 8-15 S2, 16-23 N,
// 24 CE-sum, 25 anyPred. predS/tgtS: double[2048] (j = blk&1023, b = blk>>10).
// ---------------------------------------------------------------------------
__global__ __launch_bounds__(256) void k_chds(const float* __restrict__ in,
                                              const int* __restrict__ tg,
                                              const float* __restrict__ f,
                                              float* __restrict__ statP,
                                              double* __restrict__ predS,
                                              double* __restrict__ tgtS) {
    __shared__ float part[4][27];
    __shared__ int af;
    if (threadIdx.x == 0) af = 0;
    __syncthreads();

    int blk = blockIdx.x;                       // 0..2047
    int v = blk * 256 + threadIdx.x;
    int b = v >> 18;
    int r = v & (NVOX - 1);
    int t = tg[v];
    int lane = threadIdx.x & 63;
    int wid = threadIdx.x >> 6;

    float xs[8];
#pragma unroll
    for (int c = 0; c < 8; ++c) xs[c] = in[(b * 8 + c) * NVOX + r];
    float mx = xs[0];
#pragma unroll
    for (int c = 1; c < 8; ++c) mx = fmaxf(mx, xs[c]);
    float se = 0.f;
#pragma unroll
    for (int c = 0; c < 8; ++c) se += expf(xs[c] - mx);
    float inv = 1.f / se;
    float lse = mx + logf(se);
    float xt = xs[0];
#pragma unroll
    for (int c = 1; c < 8; ++c) xt = (t == c) ? xs[c] : xt;

    bool anyP = false;
    float red[25];
#pragma unroll
    for (int c = 0; c < 8; ++c) {
        float p = expf(xs[c] - mx) * inv;
        red[c] = p;
        red[8 + c] = (t == c) ? p : 0.f;
        red[16 + c] = (t == c) ? 1.f : 0.f;
        anyP = anyP || (xs[c] > 0.5f);
    }
    red[24] = lse - xt;

    // reduce the 25 stat chains first (frees red[] before the HD loads)
#pragma unroll
    for (int k = 0; k < 25; ++k) {
        float s = red[k];
        s += __shfl_down(s, 32);
        s += __shfl_down(s, 16);
        s += __shfl_down(s, 8);
        s += __shfl_down(s, 4);
        s += __shfl_down(s, 2);
        s += __shfl_down(s, 1);
        red[k] = s;
    }
    bool wav = __any(anyP);
    if (lane == 0) {
#pragma unroll
        for (int k = 0; k < 25; ++k) part[wid][k] = red[k];
        if (wav) atomicOr(&af, 1);
    }

    // HD: C-axis min-plus + e^2 weighting, pred/tgt separated
    float e2[8];
#pragma unroll
    for (int c = 0; c < 8; ++c) {
        float e = xs[c] - ((t == c) ? 1.f : 0.f);
        e2[c] = e * e;
    }
    float accP = 0.f, accT = 0.f;
#pragma unroll
    for (int m = 0; m < 4; ++m) {
        float fm[8];
#pragma unroll
        for (int c = 0; c < 8; ++c)
            fm[c] = f[(size_t)m * FM + (b * 8 + c) * NVOX + r];
        float am = 0.f;
#pragma unroll
        for (int i = 0; i < 8; ++i) {
            float d = 1e9f;
#pragma unroll
            for (int j = 0; j < 8; ++j)
                d = fminf(d, fm[j] + (float)((i - j) * (i - j)));
            am += e2[i] * d;
        }
        if (m & 1) accT += am; else accP += am;
    }
#pragma unroll
    for (int off = 32; off >= 1; off >>= 1) {
        accP += __shfl_down(accP, off);
        accT += __shfl_down(accT, off);
    }
    if (lane == 0) { part[wid][25] = accP; part[wid][26] = accT; }
    __syncthreads();

    int j = blk & 1023;
    if (threadIdx.x < 25)
        statP[(b * 26 + threadIdx.x) * 1024 + j] =
            part[0][threadIdx.x] + part[1][threadIdx.x] +
            part[2][threadIdx.x] + part[3][threadIdx.x];
    if (threadIdx.x == 25)
        statP[(b * 26 + 25) * 1024 + j] = af ? 1.f : 0.f;
    if (threadIdx.x == 26)
        predS[blk] = (double)part[0][25] + (double)part[1][25] +
                     (double)part[2][25] + (double)part[3][25];
    if (threadIdx.x == 27)
        tgtS[blk] = (double)part[0][26] + (double)part[1][26] +
                    (double)part[2][26] + (double)part[3][26];
}

// ---------------------------------------------------------------------------
// Kernel 4: reduce partial rows + assemble scalar loss.
// ---------------------------------------------------------------------------
__global__ __launch_bounds__(256) void k_final3(const float* __restrict__ statP,
                                                const double* __restrict__ predS,
                                                const double* __restrict__ tgtS,
                                                float* __restrict__ out) {
    __shared__ float rs[52];
    __shared__ double rd[4];
    int tid = threadIdx.x;
    int w = tid >> 6;
    int lane = tid & 63;

    for (int row = w; row < 52; row += 4) {
        const float* p = statP + row * 1024;
        float s = 0.f;
#pragma unroll
        for (int k = 0; k < 16; ++k) s += p[k * 64 + lane];
        s += __shfl_down(s, 32);
        s += __shfl_down(s, 16);
        s += __shfl_down(s, 8);
        s += __shfl_down(s, 4);
        s += __shfl_down(s, 2);
        s += __shfl_down(s, 1);
        if (lane == 0) rs[row] = s;
    }
    {
        const double* p = (w < 2) ? (predS + w * 1024) : (tgtS + (w - 2) * 1024);
        double s = 0.0;
#pragma unroll
        for (int k = 0; k < 16; ++k) s += p[k * 64 + lane];
        s += __shfl_down(s, 32);
        s += __shfl_down(s, 16);
        s += __shfl_down(s, 8);
        s += __shfl_down(s, 4);
        s += __shfl_down(s, 2);
        s += __shfl_down(s, 1);
        if (lane == 0) rd[w] = s;
    }
    __syncthreads();

    if (tid == 0) {
        bool fP0 = rs[0 * 26 + 25] > 0.f;
        bool fP1 = rs[1 * 26 + 25] > 0.f;
        double h = (fP0 ? rd[0] : 0.0) + (fP1 ? rd[1] : 0.0) + rd[2] + rd[3];
        float dsum = 0.f;
        for (int c = 1; c < 8; ++c) {
            float sc = 0.f;
            for (int b = 0; b < 2; ++b) {
                float S1 = rs[b * 26 + c];
                float S2 = rs[b * 26 + 8 + c];
                float Nc = rs[b * 26 + 16 + c];
                sc += 2.f * S2 / (2.f * S2 + (S1 - S2) + (Nc - S2) + 1e-5f);
            }
            dsum += sc * 0.5f;
        }
        float dice = 1.f - dsum / 7.f;
        float ce = (rs[0 * 26 + 24] + rs[1 * 26 + 24]) / 524288.f;
        out[0] = dice + ce + (float)(h / 4194304.0);
    }
}

// ===========================================================================
// FALLBACK PATH (small workspace) — legacy kernels, verified absmax 0.0
// ===========================================================================
__global__ __launch_bounds__(256, 4) void k_stats(const float* __restrict__ in,
                                                  const int* __restrict__ tg,
                                                  float* __restrict__ accF,
                                                  int* __restrict__ flags) {
    int r = blockIdx.x * 256 + threadIdx.x;
    int lane = threadIdx.x & 63;
    int wid = threadIdx.x >> 6;
    __shared__ float part[4][25];
    __shared__ int af;

    for (int b = 0; b < 2; ++b) {
        int t = tg[b * NVOX + r];
        float xs[8];
#pragma unroll
        for (int c = 0; c < 8; ++c) xs[c] = in[(b * 8 + c) * NVOX + r];
        float mx = xs[0];
#pragma unroll
        for (int c = 1; c < 8; ++c) mx = fmaxf(mx, xs[c]);
        float ex[8];
        float se = 0.f;
#pragma unroll
        for (int c = 0; c < 8; ++c) { ex[c] = expf(xs[c] - mx); se += ex[c]; }
        float inv = 1.f / se;
        float lse = mx + logf(se);
        float xt = xs[0];
#pragma unroll
        for (int c = 1; c < 8; ++c) xt = (t == c) ? xs[c] : xt;
        bool anyP = false;
        float red[25];
#pragma unroll
        for (int c = 0; c < 8; ++c) {
            float p = ex[c] * inv;
            red[c] = p;
            red[8 + c] = (t == c) ? p : 0.f;
            red[16 + c] = (t == c) ? 1.f : 0.f;
            anyP = anyP || (xs[c] > 0.5f);
        }
        red[24] = lse - xt;
#pragma unroll
        for (int k = 0; k < 25; ++k) {
            float s = red[k];
            s += __shfl_down(s, 32);
            s += __shfl_down(s, 16);
            s += __shfl_down(s, 8);
            s += __shfl_down(s, 4);
            s += __shfl_down(s, 2);
            s += __shfl_down(s, 1);
            red[k] = s;
        }
        if (threadIdx.x == 0) af = 0;
        __syncthreads();
        bool wav = __any(anyP);
        if (lane == 0) {
#pragma unroll
            for (int k = 0; k < 25; ++k) part[wid][k] = red[k];
            if (wav) atomicOr(&af, 1);
        }
        __syncthreads();
        if (threadIdx.x < 25) {
            float s = part[0][threadIdx.x] + part[1][threadIdx.x] +
                      part[2][threadIdx.x] + part[3][threadIdx.x];
            atomicAdd(&accF[b * 25 + threadIdx.x], s);
        }
        if (threadIdx.x == 0 && af) atomicOr(&flags[b], 1);
        __syncthreads();
    }
}

template <int M0>
__global__ __launch_bounds__(64) void k_mask_zy(const float* __restrict__ in,
                                                const int* __restrict__ tg,
                                                float* __restrict__ f) {
    __shared__ float tile[64 * 65];
    int blk = blockIdx.x;
    int m = M0 + (blk >> 10);
    int s = blk & 1023;
    int b = s >> 9, c = (s >> 6) & 7, x = s & 63;
    int tid = threadIdx.x;

    if ((m & 1) == 0) {
        const float* src = in + (b * 8 + c) * NVOX + x * 4096;
#pragma unroll 8
        for (int k = 0; k < 64; ++k) {
            bool fg = src[k * 64 + tid] > 0.5f;
            bool hot = (m < 2) ? fg : !fg;
            tile[k * 65 + tid] = hot ? 1e9f : 0.f;
        }
    } else {
        const int* src = tg + b * NVOX + x * 4096;
#pragma unroll 8
        for (int k = 0; k < 64; ++k) {
            bool fg = (src[k * 64 + tid] == c);
            bool hot = (m < 2) ? fg : !fg;
            tile[k * 65 + tid] = hot ? 1e9f : 0.f;
        }
    }
    __syncthreads();
    {
        float* row = &tile[tid * 65];
        float g = 1000.f;
#pragma unroll 8
        for (int z = 0; z < 64; ++z) {
            float v = row[z];
            g = (v == 0.f) ? 0.f : g + 1.f;
            row[z] = g;
        }
        g = 1000.f;
#pragma unroll 8
        for (int z = 63; z >= 0; --z) {
            float gf = row[z];
            g = (gf == 0.f) ? 0.f : g + 1.f;
            float d = fminf(gf, g);
            row[z] = (d > 63.f) ? 1e9f : d * d;
        }
    }
    __syncthreads();
    float* out = f + (size_t)(blk >> 10) * FM + (b * 8 + c) * NVOX + x * 4096;
    for (int i = 0; i < 64; ++i) {
        float d0 = tile[i * 65 + tid];
        float d = d0;
        int Ri = (int)sqrtf(d0) + 1;
        Ri = (Ri > 63) ? 63 : Ri;
        for (int dd = 1; dd <= Ri; ++dd) {
            float q = (float)(dd * dd);
            int jl = i - dd, jr = i + dd;
            float cl = (jl >= 0) ? tile[jl * 65 + tid] : 1e9f;
            float cr = (jr < 64) ? tile[jr * 65 + tid] : 1e9f;
            d = fminf(d, fminf(cl, cr) + q);
        }
        out[i * 64 + tid] = fminf(d, 1e9f);
    }
}

template <int M0>
__global__ __launch_bounds__(128, 4) void k_dtx(float* __restrict__ f) {
    __shared__ float wl[128 * 65];
    int blk = blockIdx.x;
    int mi = blk >> 9;
    int s = blk & 511;
    int plane = s >> 5;
    int y0 = (s & 31) * 2;
    int tid = threadIdx.x;
    float* fb = f + (size_t)mi * FM + plane * NVOX + y0 * 64;

#pragma unroll 8
    for (int j = 0; j < 64; ++j) wl[tid * 65 + j] = fb[j * 4096 + tid];

    float* row = &wl[tid * 65];
    for (int i = 0; i < 64; ++i) {
        float d0 = row[i];
        float d = d0;
        int Ri = (int)sqrtf(d0) + 1;
        Ri = (Ri > 63) ? 63 : Ri;
        for (int dd = 1; dd <= Ri; ++dd) {
            float q = (float)(dd * dd);
            int jl = i - dd, jr = i + dd;
            float cl = (jl >= 0) ? row[jl] : 1e9f;
            float cr = (jr < 64) ? row[jr] : 1e9f;
            d = fminf(d, fminf(cl, cr) + q);
        }
        fb[i * 4096 + tid] = fminf(d, 1e9f);
    }
}

template <int M0, int NM>
__global__ __launch_bounds__(256, 4) void k_cdt_hd(const float* __restrict__ in,
                                                   const int* __restrict__ tg,
                                                   const float* __restrict__ f,
                                                   const int* __restrict__ flags,
                                                   double* __restrict__ hd) {
    int v = blockIdx.x * 256 + threadIdx.x;
    int b = v >> 18;
    int r = v & (NVOX - 1);
    int t = tg[v];

    float e2[8];
#pragma unroll
    for (int c = 0; c < 8; ++c) {
        float e = in[(b * 8 + c) * NVOX + r] - ((t == c) ? 1.f : 0.f);
        e2[c] = e * e;
    }
    float acc = 0.f;
#pragma unroll
    for (int mi = 0; mi < NM; ++mi) {
        int m = M0 + mi;
        float fl = (m & 1) ? 1.f : (flags[b] ? 1.f : 0.f);
        float fm[8];
#pragma unroll
        for (int c = 0; c < 8; ++c)
            fm[c] = f[(size_t)mi * FM + (b * 8 + c) * NVOX + r];
        float am = 0.f;
#pragma unroll
        for (int i = 0; i < 8; ++i) {
            float d = 1e9f;
#pragma unroll
            for (int j = 0; j < 8; ++j)
                d = fminf(d, fm[j] + (float)((i - j) * (i - j)));
            am += e2[i] * d;
        }
        acc += fl * am;
    }
    float ssum = acc;
    ssum += __shfl_down(ssum, 32);
    ssum += __shfl_down(ssum, 16);
    ssum += __shfl_down(ssum, 8);
    ssum += __shfl_down(ssum, 4);
    ssum += __shfl_down(ssum, 2);
    ssum += __shfl_down(ssum, 1);
    __shared__ float part[4];
    int lane = threadIdx.x & 63;
    int wid = threadIdx.x >> 6;
    if (lane == 0) part[wid] = ssum;
    __syncthreads();
    if (threadIdx.x == 0)
        atomicAdd(hd, (double)(part[0] + part[1] + part[2] + part[3]));
}

__global__ void k_final(const float* __restrict__ accF,
                        const double* __restrict__ hd,
                        float* __restrict__ out) {
    float dsum = 0.f;
    for (int c = 1; c < 8; ++c) {
        float sc = 0.f;
        for (int b = 0; b < 2; ++b) {
            float S1 = accF[b * 25 + c];
            float S2 = accF[b * 25 + 8 + c];
            float Nc = accF[b * 25 + 16 + c];
            sc += 2.f * S2 / (2.f * S2 + (S1 - S2) + (Nc - S2) + 1e-5f);
        }
        dsum += sc * 0.5f;
    }
    float dice = 1.f - dsum / 7.f;
    float ce = (accF[24] + accF[25 + 24]) / 524288.f;
    float hdv = (float)(hd[0] / 4194304.0);
    out[0] = dice + ce + hdv;
}

template <int M0, int NM>
static void run_chunk(const float* in, const int* tg, float* f,
                      const int* flags, double* hd, hipStream_t stream) {
    k_mask_zy<M0><<<NM * 1024, 64, 0, stream>>>(in, tg, f);
    k_dtx<M0><<<NM * 512, 128, 0, stream>>>(f);
    k_cdt_hd<M0, NM><<<2048, 256, 0, stream>>>(in, tg, f, flags, hd);
}

// ---------------------------------------------------------------------------
extern "C" void kernel_launch(void* const* d_in, const int* in_sizes, int n_in,
                              void* d_out, int out_size, void* d_ws, size_t ws_size,
                              hipStream_t stream) {
    const float* in = (const float*)d_in[0];
    const int* tg = (const int*)d_in[1];
    float* out = (float*)d_out;
    float* f = (float*)d_ws;

    // fast-path partials after the 67.1 MB field array
    size_t offF = (size_t)4 * FM * 4;            // 67,108,864
    size_t need_fast = offF + 2048 * 8 * 2 + 52 * 1024 * 4;

    if (ws_size >= need_fast) {
        double* predS = (double*)((char*)d_ws + offF);
        double* tgtS = (double*)((char*)d_ws + offF + 16384);
        float* statP = (float*)((char*)d_ws + offF + 32768);
        k_zy2<<<2048, 256, 0, stream>>>(in, tg, f);
        k_xdt<<<4096, 256, 0, stream>>>(f);
        k_chds<<<2048, 256, 0, stream>>>(in, tg, f, statP, predS, tgtS);
        k_final3<<<1, 256, 0, stream>>>(statP, predS, tgtS, out);
    } else {
        size_t acc_off = ((ws_size - 256) / 256) * 256;
        char* accB = (char*)d_ws + acc_off;
        double* hd = (double*)accB;
        float* accF = (float*)(accB + 8);
        int* flags = (int*)(accB + 208);
        hipMemsetAsync(accB, 0, 256, stream);
        k_stats<<<1024, 256, 0, stream>>>(in, tg, accF, flags);
        int nm_cap = (int)(acc_off / ((size_t)FM * 4));
        if (nm_cap >= 2) {
            run_chunk<0, 2>(in, tg, f, flags, hd, stream);
            run_chunk<2, 2>(in, tg, f, flags, hd, stream);
        } else if (nm_cap >= 1) {
            run_chunk<0, 1>(in, tg, f, flags, hd, stream);
            run_chunk<1, 1>(in, tg, f, flags, hd, stream);
            run_chunk<2, 1>(in, tg, f, flags, hd, stream);
            run_chunk<3, 1>(in, tg, f, flags, hd, stream);
        }
        k_final<<<1, 1, 0, stream>>>(accF, hd, out);
    }
}

// Round 9
// 144.299 us; speedup vs baseline: 2.6735x; 1.0450x over previous
//
#include <hip/hip_runtime.h>

#define NVOX (64 * 64 * 64)          // 262144
#define FMU (16 * NVOX)              // u16 elements per packed field (B*C*XYZ)
#define FM (16 * NVOX)               // legacy float field (fallback path)

// Packed field encoding (fast path): one u16 per (src,b,c,x,y,z):
//   bit15  = membership (1 = voxel is in the fg mask)
//   b0-14  = the NONZERO side's squared distance (fg if member, bg if not);
//            32767 = "exactly 1e9" sentinel (no seed anywhere in scope).
// Invariant (holds at every exact min-plus stage): member => d_bg == 0,
// d_fg >= 1; non-member => d_fg == 0, d_bg >= 1. Max real value after all
// 3 spatial axes = 3*63^2 = 11907 < 32767. All inner loops are float and
// bit-identical to the verified rounds (absmax 0.0 in 2/4/5/6/7/8);
// pack/unpack happens only at global memory boundaries.

__device__ __forceinline__ float unpack_val(unsigned short p) {
    int v = p & 0x7fff;
    return (v == 32767) ? 1e9f : (float)v;
}

// ===========================================================================
// FAST PATH
// ===========================================================================

// ---------------------------------------------------------------------------
// Kernel 1: Z (ballot bit-trick; one ballot yields fg AND bg) + Y
// (dynamic-break min-plus, fg then bg with tile reuse) for a (src,b,c,x)
// slab. src 0 = pred, 1 = target. Writes ONE packed u16 field per src.
// 16.6 KB LDS -> 8 blocks/CU.
// ---------------------------------------------------------------------------
__global__ __launch_bounds__(256) void k_zy2(const float* __restrict__ in,
                                             const int* __restrict__ tg,
                                             unsigned short* __restrict__ f) {
    __shared__ float tile[64 * 65];            // 16.64 KB
    int blk = blockIdx.x;                       // 0..2047
    int src = blk >> 10;
    int s = blk & 1023;
    int b = s >> 9, c = (s >> 6) & 7, x = s & 63;
    int w = threadIdx.x >> 6;                   // wave 0..3
    int z = threadIdx.x & 63;                   // lane <-> z

    const float* pin = in + (b * 8 + c) * NVOX + x * 4096;
    const int* ptg = tg + b * NVOX + x * 4096;

    float dA[16], dB[16];
    bool mb[16];
#pragma unroll
    for (int k = 0; k < 16; ++k) {
        int y = k * 4 + w;
        bool member;
        if (src == 0) member = pin[y * 64 + z] > 0.5f;
        else          member = ptg[y * 64 + z] == c;
        mb[k] = member;
        unsigned long long mkA = __ballot(!member);   // fg seeds = non-members
        unsigned long long mkB = ~mkA;                // bg seeds = members
        unsigned long long sfA = mkA << (63 - z), sbA = mkA >> z;
        int dfA = sfA ? __builtin_clzll(sfA) : 64;
        int dbA = sbA ? __builtin_ctzll(sbA) : 64;
        int da = dfA < dbA ? dfA : dbA;
        unsigned long long sfB = mkB << (63 - z), sbB = mkB >> z;
        int dfB = sfB ? __builtin_clzll(sfB) : 64;
        int dbB = sbB ? __builtin_ctzll(sbB) : 64;
        int db = dfB < dbB ? dfB : dbB;
        float a2 = (da > 63) ? 1e9f : (float)(da * da);
        float b2 = (db > 63) ? 1e9f : (float)(db * db);
        tile[y * 65 + z] = a2;                  // fg first
        dA[k] = a2;
        dB[k] = b2;
    }
    __syncthreads();

    // fg Y-pass (dynamic break, exact)
    float rA[16];
#pragma unroll
    for (int k = 0; k < 16; ++k) {
        int y = k * 4 + w;
        float d = dA[k];
        int q = 1;
        for (int dd = 1; dd <= 63 && (float)q < d; ++dd) {
            int jl = y - dd, jr = y + dd;
            float cl = (jl >= 0) ? tile[jl * 65 + z] : 1e9f;
            float cr = (jr < 64) ? tile[jr * 65 + z] : 1e9f;
            d = fminf(d, fminf(cl, cr) + (float)q);
            q += 2 * dd + 1;
        }
        rA[k] = fminf(d, 1e9f);
    }
    __syncthreads();
#pragma unroll
    for (int k = 0; k < 16; ++k) tile[(k * 4 + w) * 65 + z] = dB[k];
    __syncthreads();

    // bg Y-pass + pack + store
    unsigned short* out = f + (size_t)src * FMU + (b * 8 + c) * NVOX + x * 4096;
#pragma unroll
    for (int k = 0; k < 16; ++k) {
        int y = k * 4 + w;
        float d = dB[k];
        int q = 1;
        for (int dd = 1; dd <= 63 && (float)q < d; ++dd) {
            int jl = y - dd, jr = y + dd;
            float cl = (jl >= 0) ? tile[jl * 65 + z] : 1e9f;
            float cr = (jr < 64) ? tile[jr * 65 + z] : 1e9f;
            d = fminf(d, fminf(cl, cr) + (float)q);
            q += 2 * dd + 1;
        }
        float tot = rA[k] + fminf(d, 1e9f);     // exactly one side nonzero
        int vi = (int)fminf(tot, 32767.f);
        out[y * 64 + z] = (unsigned short)((mb[k] ? 0x8000 : 0) | vi);
    }
}

// ---------------------------------------------------------------------------
// Kernel 2: X pass on the packed field. Block = (src,b,c,y); lane <-> z.
// Unpack to fg tile + bg regs, fg pass, tile reuse for bg, repack.
// ---------------------------------------------------------------------------
__global__ __launch_bounds__(256) void k_xdt(unsigned short* __restrict__ f) {
    __shared__ float tile[64 * 65];            // 16.64 KB
    int blk = blockIdx.x;                       // 0..2047
    int src = blk >> 10;
    int s = blk & 1023;
    int b = s >> 9, c = (s >> 6) & 7, y = s & 63;
    int w = threadIdx.x >> 6;
    int z = threadIdx.x & 63;

    unsigned short* base = f + (size_t)src * FMU + (b * 8 + c) * NVOX + y * 64;

    unsigned short pk[16];
    float dA0[16], dB0[16];
#pragma unroll
    for (int k = 0; k < 16; ++k) {
        int x = k * 4 + w;
        unsigned short p = base[x * 4096 + z];
        pk[k] = p;
        float fv = unpack_val(p);
        bool member = (p & 0x8000) != 0;
        float a = member ? fv : 0.f;
        float bb = member ? 0.f : fv;
        tile[x * 65 + z] = a;
        dA0[k] = a;
        dB0[k] = bb;
    }
    __syncthreads();

    float rA[16];
#pragma unroll
    for (int k = 0; k < 16; ++k) {
        int x = k * 4 + w;
        float d = dA0[k];
        int q = 1;
        for (int dd = 1; dd <= 63 && (float)q < d; ++dd) {
            int jl = x - dd, jr = x + dd;
            float cl = (jl >= 0) ? tile[jl * 65 + z] : 1e9f;
            float cr = (jr < 64) ? tile[jr * 65 + z] : 1e9f;
            d = fminf(d, fminf(cl, cr) + (float)q);
            q += 2 * dd + 1;
        }
        rA[k] = fminf(d, 1e9f);
    }
    __syncthreads();
#pragma unroll
    for (int k = 0; k < 16; ++k) tile[(k * 4 + w) * 65 + z] = dB0[k];
    __syncthreads();

#pragma unroll
    for (int k = 0; k < 16; ++k) {
        int x = k * 4 + w;
        float d = dB0[k];
        int q = 1;
        for (int dd = 1; dd <= 63 && (float)q < d; ++dd) {
            int jl = x - dd, jr = x + dd;
            float cl = (jl >= 0) ? tile[jl * 65 + z] : 1e9f;
            float cr = (jr < 64) ? tile[jr * 65 + z] : 1e9f;
            d = fminf(d, fminf(cl, cr) + (float)q);
            q += 2 * dd + 1;
        }
        float tot = rA[k] + fminf(d, 1e9f);
        int vi = (int)fminf(tot, 32767.f);
        base[x * 4096 + z] = (unsigned short)((pk[k] & 0x8000) | vi);
    }
}

// ---------------------------------------------------------------------------
// Kernel 3: fused C-axis DT + HD + softmax stats + CE + pred-has-fg.
// Reads the 2 packed u16 fields, unpacks fg/bg per channel in registers.
// Per-block partial slots -> zero atomic contention.
// ---------------------------------------------------------------------------
__global__ __launch_bounds__(256) void k_chds(const float* __restrict__ in,
                                              const int* __restrict__ tg,
                                              const unsigned short* __restrict__ f,
                                              float* __restrict__ statP,
                                              double* __restrict__ predS,
                                              double* __restrict__ tgtS) {
    __shared__ float part[4][27];
    __shared__ int af;
    if (threadIdx.x == 0) af = 0;
    __syncthreads();

    int blk = blockIdx.x;                       // 0..2047
    int v = blk * 256 + threadIdx.x;
    int b = v >> 18;
    int r = v & (NVOX - 1);
    int t = tg[v];
    int lane = threadIdx.x & 63;
    int wid = threadIdx.x >> 6;

    float xs[8];
#pragma unroll
    for (int c = 0; c < 8; ++c) xs[c] = in[(b * 8 + c) * NVOX + r];
    float mx = xs[0];
#pragma unroll
    for (int c = 1; c < 8; ++c) mx = fmaxf(mx, xs[c]);
    float se = 0.f;
#pragma unroll
    for (int c = 0; c < 8; ++c) se += expf(xs[c] - mx);
    float inv = 1.f / se;
    float lse = mx + logf(se);
    float xt = xs[0];
#pragma unroll
    for (int c = 1; c < 8; ++c) xt = (t == c) ? xs[c] : xt;

    bool anyP = false;
    float red[25];
#pragma unroll
    for (int c = 0; c < 8; ++c) {
        float p = expf(xs[c] - mx) * inv;
        red[c] = p;
        red[8 + c] = (t == c) ? p : 0.f;
        red[16 + c] = (t == c) ? 1.f : 0.f;
        anyP = anyP || (xs[c] > 0.5f);
    }
    red[24] = lse - xt;

#pragma unroll
    for (int k = 0; k < 25; ++k) {
        float s = red[k];
        s += __shfl_down(s, 32);
        s += __shfl_down(s, 16);
        s += __shfl_down(s, 8);
        s += __shfl_down(s, 4);
        s += __shfl_down(s, 2);
        s += __shfl_down(s, 1);
        red[k] = s;
    }
    bool wav = __any(anyP);
    if (lane == 0) {
#pragma unroll
        for (int k = 0; k < 25; ++k) part[wid][k] = red[k];
        if (wav) atomicOr(&af, 1);
    }

    // HD: unpack fg/bg, C-axis min-plus on each, e^2 weighting.
    float e2[8];
#pragma unroll
    for (int c = 0; c < 8; ++c) {
        float e = xs[c] - ((t == c) ? 1.f : 0.f);
        e2[c] = e * e;
    }
    float accP = 0.f, accT = 0.f;
#pragma unroll
    for (int src = 0; src < 2; ++src) {
        float fmA[8], fmB[8];
#pragma unroll
        for (int c = 0; c < 8; ++c) {
            unsigned short p = f[(size_t)src * FMU + (b * 8 + c) * NVOX + r];
            float fv = unpack_val(p);
            bool member = (p & 0x8000) != 0;
            fmA[c] = member ? fv : 0.f;
            fmB[c] = member ? 0.f : fv;
        }
        float am = 0.f;
#pragma unroll
        for (int i = 0; i < 8; ++i) {
            float da = 1e9f, db = 1e9f;
#pragma unroll
            for (int j = 0; j < 8; ++j) {
                float q = (float)((i - j) * (i - j));
                da = fminf(da, fmA[j] + q);
                db = fminf(db, fmB[j] + q);
            }
            am += e2[i] * (da + db);
        }
        if (src) accT += am; else accP += am;
    }
#pragma unroll
    for (int off = 32; off >= 1; off >>= 1) {
        accP += __shfl_down(accP, off);
        accT += __shfl_down(accT, off);
    }
    if (lane == 0) { part[wid][25] = accP; part[wid][26] = accT; }
    __syncthreads();

    int j = blk & 1023;
    if (threadIdx.x < 25)
        statP[(b * 26 + threadIdx.x) * 1024 + j] =
            part[0][threadIdx.x] + part[1][threadIdx.x] +
            part[2][threadIdx.x] + part[3][threadIdx.x];
    if (threadIdx.x == 25)
        statP[(b * 26 + 25) * 1024 + j] = af ? 1.f : 0.f;
    if (threadIdx.x == 26)
        predS[blk] = (double)part[0][25] + (double)part[1][25] +
                     (double)part[2][25] + (double)part[3][25];
    if (threadIdx.x == 27)
        tgtS[blk] = (double)part[0][26] + (double)part[1][26] +
                    (double)part[2][26] + (double)part[3][26];
}

// ---------------------------------------------------------------------------
// Kernel 4: reduce partial rows + assemble scalar loss.
// ---------------------------------------------------------------------------
__global__ __launch_bounds__(256) void k_final3(const float* __restrict__ statP,
                                                const double* __restrict__ predS,
                                                const double* __restrict__ tgtS,
                                                float* __restrict__ out) {
    __shared__ float rs[52];
    __shared__ double rd[4];
    int tid = threadIdx.x;
    int w = tid >> 6;
    int lane = tid & 63;

    for (int row = w; row < 52; row += 4) {
        const float* p = statP + row * 1024;
        float s = 0.f;
#pragma unroll
        for (int k = 0; k < 16; ++k) s += p[k * 64 + lane];
        s += __shfl_down(s, 32);
        s += __shfl_down(s, 16);
        s += __shfl_down(s, 8);
        s += __shfl_down(s, 4);
        s += __shfl_down(s, 2);
        s += __shfl_down(s, 1);
        if (lane == 0) rs[row] = s;
    }
    {
        const double* p = (w < 2) ? (predS + w * 1024) : (tgtS + (w - 2) * 1024);
        double s = 0.0;
#pragma unroll
        for (int k = 0; k < 16; ++k) s += p[k * 64 + lane];
        s += __shfl_down(s, 32);
        s += __shfl_down(s, 16);
        s += __shfl_down(s, 8);
        s += __shfl_down(s, 4);
        s += __shfl_down(s, 2);
        s += __shfl_down(s, 1);
        if (lane == 0) rd[w] = s;
    }
    __syncthreads();

    if (tid == 0) {
        bool fP0 = rs[0 * 26 + 25] > 0.f;
        bool fP1 = rs[1 * 26 + 25] > 0.f;
        double h = (fP0 ? rd[0] : 0.0) + (fP1 ? rd[1] : 0.0) + rd[2] + rd[3];
        float dsum = 0.f;
        for (int c = 1; c < 8; ++c) {
            float sc = 0.f;
            for (int b = 0; b < 2; ++b) {
                float S1 = rs[b * 26 + c];
                float S2 = rs[b * 26 + 8 + c];
                float Nc = rs[b * 26 + 16 + c];
                sc += 2.f * S2 / (2.f * S2 + (S1 - S2) + (Nc - S2) + 1e-5f);
            }
            dsum += sc * 0.5f;
        }
        float dice = 1.f - dsum / 7.f;
        float ce = (rs[0 * 26 + 24] + rs[1 * 26 + 24]) / 524288.f;
        out[0] = dice + ce + (float)(h / 4194304.0);
    }
}

// ===========================================================================
// FALLBACK PATH (small workspace) — legacy float-field kernels (absmax 0.0)
// ===========================================================================
__global__ __launch_bounds__(256, 4) void k_stats(const float* __restrict__ in,
                                                  const int* __restrict__ tg,
                                                  float* __restrict__ accF,
                                                  int* __restrict__ flags) {
    int r = blockIdx.x * 256 + threadIdx.x;
    int lane = threadIdx.x & 63;
    int wid = threadIdx.x >> 6;
    __shared__ float part[4][25];
    __shared__ int af;

    for (int b = 0; b < 2; ++b) {
        int t = tg[b * NVOX + r];
        float xs[8];
#pragma unroll
        for (int c = 0; c < 8; ++c) xs[c] = in[(b * 8 + c) * NVOX + r];
        float mx = xs[0];
#pragma unroll
        for (int c = 1; c < 8; ++c) mx = fmaxf(mx, xs[c]);
        float ex[8];
        float se = 0.f;
#pragma unroll
        for (int c = 0; c < 8; ++c) { ex[c] = expf(xs[c] - mx); se += ex[c]; }
        float inv = 1.f / se;
        float lse = mx + logf(se);
        float xt = xs[0];
#pragma unroll
        for (int c = 1; c < 8; ++c) xt = (t == c) ? xs[c] : xt;
        bool anyP = false;
        float red[25];
#pragma unroll
        for (int c = 0; c < 8; ++c) {
            float p = ex[c] * inv;
            red[c] = p;
            red[8 + c] = (t == c) ? p : 0.f;
            red[16 + c] = (t == c) ? 1.f : 0.f;
            anyP = anyP || (xs[c] > 0.5f);
        }
        red[24] = lse - xt;
#pragma unroll
        for (int k = 0; k < 25; ++k) {
            float s = red[k];
            s += __shfl_down(s, 32);
            s += __shfl_down(s, 16);
            s += __shfl_down(s, 8);
            s += __shfl_down(s, 4);
            s += __shfl_down(s, 2);
            s += __shfl_down(s, 1);
            red[k] = s;
        }
        if (threadIdx.x == 0) af = 0;
        __syncthreads();
        bool wav = __any(anyP);
        if (lane == 0) {
#pragma unroll
            for (int k = 0; k < 25; ++k) part[wid][k] = red[k];
            if (wav) atomicOr(&af, 1);
        }
        __syncthreads();
        if (threadIdx.x < 25) {
            float s = part[0][threadIdx.x] + part[1][threadIdx.x] +
                      part[2][threadIdx.x] + part[3][threadIdx.x];
            atomicAdd(&accF[b * 25 + threadIdx.x], s);
        }
        if (threadIdx.x == 0 && af) atomicOr(&flags[b], 1);
        __syncthreads();
    }
}

template <int M0>
__global__ __launch_bounds__(64) void k_mask_zy(const float* __restrict__ in,
                                                const int* __restrict__ tg,
                                                float* __restrict__ f) {
    __shared__ float tile[64 * 65];
    int blk = blockIdx.x;
    int m = M0 + (blk >> 10);
    int s = blk & 1023;
    int b = s >> 9, c = (s >> 6) & 7, x = s & 63;
    int tid = threadIdx.x;

    if ((m & 1) == 0) {
        const float* src = in + (b * 8 + c) * NVOX + x * 4096;
#pragma unroll 8
        for (int k = 0; k < 64; ++k) {
            bool fg = src[k * 64 + tid] > 0.5f;
            bool hot = (m < 2) ? fg : !fg;
            tile[k * 65 + tid] = hot ? 1e9f : 0.f;
        }
    } else {
        const int* src = tg + b * NVOX + x * 4096;
#pragma unroll 8
        for (int k = 0; k < 64; ++k) {
            bool fg = (src[k * 64 + tid] == c);
            bool hot = (m < 2) ? fg : !fg;
            tile[k * 65 + tid] = hot ? 1e9f : 0.f;
        }
    }
    __syncthreads();
    {
        float* row = &tile[tid * 65];
        float g = 1000.f;
#pragma unroll 8
        for (int z = 0; z < 64; ++z) {
            float v = row[z];
            g = (v == 0.f) ? 0.f : g + 1.f;
            row[z] = g;
        }
        g = 1000.f;
#pragma unroll 8
        for (int z = 63; z >= 0; --z) {
            float gf = row[z];
            g = (gf == 0.f) ? 0.f : g + 1.f;
            float d = fminf(gf, g);
            row[z] = (d > 63.f) ? 1e9f : d * d;
        }
    }
    __syncthreads();
    float* out = f + (size_t)(blk >> 10) * FM + (b * 8 + c) * NVOX + x * 4096;
    for (int i = 0; i < 64; ++i) {
        float d0 = tile[i * 65 + tid];
        float d = d0;
        int Ri = (int)sqrtf(d0) + 1;
        Ri = (Ri > 63) ? 63 : Ri;
        for (int dd = 1; dd <= Ri; ++dd) {
            float q = (float)(dd * dd);
            int jl = i - dd, jr = i + dd;
            float cl = (jl >= 0) ? tile[jl * 65 + tid] : 1e9f;
            float cr = (jr < 64) ? tile[jr * 65 + tid] : 1e9f;
            d = fminf(d, fminf(cl, cr) + q);
        }
        out[i * 64 + tid] = fminf(d, 1e9f);
    }
}

template <int M0>
__global__ __launch_bounds__(128, 4) void k_dtx(float* __restrict__ f) {
    __shared__ float wl[128 * 65];
    int blk = blockIdx.x;
    int mi = blk >> 9;
    int s = blk & 511;
    int plane = s >> 5;
    int y0 = (s & 31) * 2;
    int tid = threadIdx.x;
    float* fb = f + (size_t)mi * FM + plane * NVOX + y0 * 64;

#pragma unroll 8
    for (int j = 0; j < 64; ++j) wl[tid * 65 + j] = fb[j * 4096 + tid];

    float* row = &wl[tid * 65];
    for (int i = 0; i < 64; ++i) {
        float d0 = row[i];
        float d = d0;
        int Ri = (int)sqrtf(d0) + 1;
        Ri = (Ri > 63) ? 63 : Ri;
        for (int dd = 1; dd <= Ri; ++dd) {
            float q = (float)(dd * dd);
            int jl = i - dd, jr = i + dd;
            float cl = (jl >= 0) ? row[jl] : 1e9f;
            float cr = (jr < 64) ? row[jr] : 1e9f;
            d = fminf(d, fminf(cl, cr) + q);
        }
        fb[i * 4096 + tid] = fminf(d, 1e9f);
    }
}

template <int M0, int NM>
__global__ __launch_bounds__(256, 4) void k_cdt_hd(const float* __restrict__ in,
                                                   const int* __restrict__ tg,
                                                   const float* __restrict__ f,
                                                   const int* __restrict__ flags,
                                                   double* __restrict__ hd) {
    int v = blockIdx.x * 256 + threadIdx.x;
    int b = v >> 18;
    int r = v & (NVOX - 1);
    int t = tg[v];

    float e2[8];
#pragma unroll
    for (int c = 0; c < 8; ++c) {
        float e = in[(b * 8 + c) * NVOX + r] - ((t == c) ? 1.f : 0.f);
        e2[c] = e * e;
    }
    float acc = 0.f;
#pragma unroll
    for (int mi = 0; mi < NM; ++mi) {
        int m = M0 + mi;
        float fl = (m & 1) ? 1.f : (flags[b] ? 1.f : 0.f);
        float fm[8];
#pragma unroll
        for (int c = 0; c < 8; ++c)
            fm[c] = f[(size_t)mi * FM + (b * 8 + c) * NVOX + r];
        float am = 0.f;
#pragma unroll
        for (int i = 0; i < 8; ++i) {
            float d = 1e9f;
#pragma unroll
            for (int j = 0; j < 8; ++j)
                d = fminf(d, fm[j] + (float)((i - j) * (i - j)));
            am += e2[i] * d;
        }
        acc += fl * am;
    }
    float ssum = acc;
    ssum += __shfl_down(ssum, 32);
    ssum += __shfl_down(ssum, 16);
    ssum += __shfl_down(ssum, 8);
    ssum += __shfl_down(ssum, 4);
    ssum += __shfl_down(ssum, 2);
    ssum += __shfl_down(ssum, 1);
    __shared__ float part[4];
    int lane = threadIdx.x & 63;
    int wid = threadIdx.x >> 6;
    if (lane == 0) part[wid] = ssum;
    __syncthreads();
    if (threadIdx.x == 0)
        atomicAdd(hd, (double)(part[0] + part[1] + part[2] + part[3]));
}

__global__ void k_final(const float* __restrict__ accF,
                        const double* __restrict__ hd,
                        float* __restrict__ out) {
    float dsum = 0.f;
    for (int c = 1; c < 8; ++c) {
        float sc = 0.f;
        for (int b = 0; b < 2; ++b) {
            float S1 = accF[b * 25 + c];
            float S2 = accF[b * 25 + 8 + c];
            float Nc = accF[b * 25 + 16 + c];
            sc += 2.f * S2 / (2.f * S2 + (S1 - S2) + (Nc - S2) + 1e-5f);
        }
        dsum += sc * 0.5f;
    }
    float dice = 1.f - dsum / 7.f;
    float ce = (accF[24] + accF[25 + 24]) / 524288.f;
    float hdv = (float)(hd[0] / 4194304.0);
    out[0] = dice + ce + hdv;
}

template <int M0, int NM>
static void run_chunk(const float* in, const int* tg, float* f,
                      const int* flags, double* hd, hipStream_t stream) {
    k_mask_zy<M0><<<NM * 1024, 64, 0, stream>>>(in, tg, f);
    k_dtx<M0><<<NM * 512, 128, 0, stream>>>(f);
    k_cdt_hd<M0, NM><<<2048, 256, 0, stream>>>(in, tg, f, flags, hd);
}

// ---------------------------------------------------------------------------
extern "C" void kernel_launch(void* const* d_in, const int* in_sizes, int n_in,
                              void* d_out, int out_size, void* d_ws, size_t ws_size,
                              hipStream_t stream) {
    const float* in = (const float*)d_in[0];
    const int* tg = (const int*)d_in[1];
    float* out = (float*)d_out;

    // fast-path layout: packed u16 fields (2 x 8.4 MB), then partials
    size_t offF = (size_t)2 * FMU * 2;           // 16,777,216 bytes
    size_t need_fast = offF + 16384 + 16384 + 52 * 1024 * 4;

    if (ws_size >= need_fast) {
        unsigned short* fu = (unsigned short*)d_ws;
        double* predS = (double*)((char*)d_ws + offF);
        double* tgtS = (double*)((char*)d_ws + offF + 16384);
        float* statP = (float*)((char*)d_ws + offF + 32768);
        k_zy2<<<2048, 256, 0, stream>>>(in, tg, fu);
        k_xdt<<<2048, 256, 0, stream>>>(fu);
        k_chds<<<2048, 256, 0, stream>>>(in, tg, fu, statP, predS, tgtS);
        k_final3<<<1, 256, 0, stream>>>(statP, predS, tgtS, out);
    } else {
        float* f = (float*)d_ws;
        size_t acc_off = ((ws_size - 256) / 256) * 256;
        char* accB = (char*)d_ws + acc_off;
        double* hd = (double*)accB;
        float* accF = (float*)(accB + 8);
        int* flags = (int*)(accB + 208);
        hipMemsetAsync(accB, 0, 256, stream);
        k_stats<<<1024, 256, 0, stream>>>(in, tg, accF, flags);
        int nm_cap = (int)(acc_off / ((size_t)FM * 4));
        if (nm_cap >= 2) {
            run_chunk<0, 2>(in, tg, f, flags, hd, stream);
            run_chunk<2, 2>(in, tg, f, flags, hd, stream);
        } else if (nm_cap >= 1) {
            run_chunk<0, 1>(in, tg, f, flags, hd, stream);
            run_chunk<1, 1>(in, tg, f, flags, hd, stream);
            run_chunk<2, 1>(in, tg, f, flags, hd, stream);
            run_chunk<3, 1>(in, tg, f, flags, hd, stream);
        }
        k_final<<<1, 1, 0, stream>>>(accF, hd, out);
    }
}

// Round 10
// 139.823 us; speedup vs baseline: 2.7591x; 1.0320x over previous
//
#include <hip/hip_runtime.h>

#define NVOX (64 * 64 * 64)          // 262144
#define FMU (16 * NVOX)              // u16 elements per packed field (B*C*XYZ)
#define FM (16 * NVOX)               // legacy float field (fallback path)

// Packed field encoding (fast path): one u16 per (src,b,c,x,y,z):
//   bit15  = membership (1 = voxel is in the fg mask)
//   b0-14  = the NONZERO side's squared distance (fg if member, bg if not);
//            32767 = "exactly 1e9" sentinel.
// Invariant (holds at every exact min-plus stage): member => d_bg == 0;
// non-member => d_fg == 0. Max real value 3*63^2 = 11907 < 32767.
// All inner loops are float and bit-identical to the verified rounds
// (absmax 0.0 in 2/4/5/6/7/8/9); pack/unpack only at global boundaries.
//
// DT window loops run with LANES ALONG THE AXIS (lane = y for the Y pass,
// lane = x for the X pass): all 64 lanes share one column's seed-gap
// structure, so the wave-max trip count ~= column max (divergence fix).
// Outputs are staged packed in LDS and stored with lanes = z (coalesced).

__device__ __forceinline__ float unpack_val(unsigned short p) {
    int v = p & 0x7fff;
    return (v == 32767) ? 1e9f : (float)v;
}

// ===========================================================================
// FAST PATH
// ===========================================================================

// ---------------------------------------------------------------------------
// Kernel 1: Z (ballot; one ballot yields fg AND bg) + Y (lane-transposed
// dynamic-break min-plus) for a (src,b,c,x) slab. Writes packed u16 field.
// ---------------------------------------------------------------------------
__global__ __launch_bounds__(256) void k_zy2(const float* __restrict__ in,
                                             const int* __restrict__ tg,
                                             unsigned short* __restrict__ f) {
    __shared__ float tile[64 * 65];            // 16.64 KB
    unsigned short* tile16 = (unsigned short*)tile;
    int blk = blockIdx.x;                       // 0..2047
    int src = blk >> 10;
    int s = blk & 1023;
    int b = s >> 9, c = (s >> 6) & 7, x = s & 63;
    int w = threadIdx.x >> 6;                   // wave 0..3
    int lane = threadIdx.x & 63;

    const float* pin = in + (b * 8 + c) * NVOX + x * 4096;
    const int* ptg = tg + b * NVOX + x * 4096;

    // Phase 1 (lanes = z): ballot Z-scan; fg dist^2 -> tile, bg -> regs.
    float dB[16];
#pragma unroll
    for (int k = 0; k < 16; ++k) {
        int y = k * 4 + w;
        bool member;
        if (src == 0) member = pin[y * 64 + lane] > 0.5f;
        else          member = ptg[y * 64 + lane] == c;
        unsigned long long mkA = __ballot(!member);   // fg seeds = non-members
        unsigned long long mkB = ~mkA;                // bg seeds = members
        unsigned long long sfA = mkA << (63 - lane), sbA = mkA >> lane;
        int dfA = sfA ? __builtin_clzll(sfA) : 64;
        int dbA = sbA ? __builtin_ctzll(sbA) : 64;
        int da = dfA < dbA ? dfA : dbA;
        unsigned long long sfB = mkB << (63 - lane), sbB = mkB >> lane;
        int dfB = sfB ? __builtin_clzll(sfB) : 64;
        int dbB = sbB ? __builtin_ctzll(sbB) : 64;
        int db = dfB < dbB ? dfB : dbB;
        tile[y * 65 + lane] = (da > 63) ? 1e9f : (float)(da * da);
        dB[k] = (db > 63) ? 1e9f : (float)(db * db);
    }
    __syncthreads();

    // Phase 2 (lanes = y): fg Y-pass, z = k*4+w.
    float rA[16];
#pragma unroll
    for (int k = 0; k < 16; ++k) {
        int z = k * 4 + w;
        float d = tile[lane * 65 + z];
        int q = 1;
        for (int dd = 1; dd <= 63 && (float)q < d; ++dd) {
            int jl = lane - dd, jr = lane + dd;
            float cl = (jl >= 0) ? tile[jl * 65 + z] : 1e9f;
            float cr = (jr < 64) ? tile[jr * 65 + z] : 1e9f;
            d = fminf(d, fminf(cl, cr) + (float)q);
            q += 2 * dd + 1;
        }
        rA[k] = fminf(d, 1e9f);
    }
    __syncthreads();

    // Phase 3 (lanes = z): refill tile with bg.
#pragma unroll
    for (int k = 0; k < 16; ++k) tile[(k * 4 + w) * 65 + lane] = dB[k];
    __syncthreads();

    // Phase 4 (lanes = y): bg Y-pass.
    float rB[16];
#pragma unroll
    for (int k = 0; k < 16; ++k) {
        int z = k * 4 + w;
        float d = tile[lane * 65 + z];
        int q = 1;
        for (int dd = 1; dd <= 63 && (float)q < d; ++dd) {
            int jl = lane - dd, jr = lane + dd;
            float cl = (jl >= 0) ? tile[jl * 65 + z] : 1e9f;
            float cr = (jr < 64) ? tile[jr * 65 + z] : 1e9f;
            d = fminf(d, fminf(cl, cr) + (float)q);
            q += 2 * dd + 1;
        }
        rB[k] = fminf(d, 1e9f);
    }
    __syncthreads();

    // Phase 5 (lanes = y): pack into LDS (member <=> bg dist == 0).
#pragma unroll
    for (int k = 0; k < 16; ++k) {
        int z = k * 4 + w;
        float tot = rA[k] + rB[k];
        int vi = (int)fminf(tot, 32767.f);
        tile16[lane * 65 + z] =
            (unsigned short)(((rB[k] == 0.f) ? 0x8000 : 0) | vi);
    }
    __syncthreads();

    // Phase 6 (lanes = z): coalesced store.
    unsigned short* out = f + (size_t)src * FMU + (b * 8 + c) * NVOX + x * 4096;
#pragma unroll
    for (int k = 0; k < 16; ++k) {
        int y = k * 4 + w;
        out[y * 64 + lane] = tile16[y * 65 + lane];
    }
}

// ---------------------------------------------------------------------------
// Kernel 2: X pass (lane-transposed) on the packed field. Block=(src,b,c,y).
// ---------------------------------------------------------------------------
__global__ __launch_bounds__(256) void k_xdt(unsigned short* __restrict__ f) {
    __shared__ float tile[64 * 65];            // 16.64 KB
    unsigned short* tile16 = (unsigned short*)tile;
    int blk = blockIdx.x;                       // 0..2047
    int src = blk >> 10;
    int s = blk & 1023;
    int b = s >> 9, c = (s >> 6) & 7, y = s & 63;
    int w = threadIdx.x >> 6;
    int lane = threadIdx.x & 63;

    unsigned short* base = f + (size_t)src * FMU + (b * 8 + c) * NVOX + y * 64;

    // Phase 1 (lanes = z): coalesced load + unpack; fg -> tile, bg -> regs.
    float dB0[16];
#pragma unroll
    for (int k = 0; k < 16; ++k) {
        int x = k * 4 + w;
        unsigned short p = base[x * 4096 + lane];
        float fv = unpack_val(p);
        bool member = (p & 0x8000) != 0;
        tile[x * 65 + lane] = member ? fv : 0.f;
        dB0[k] = member ? 0.f : fv;
    }
    __syncthreads();

    // Phase 2 (lanes = x): fg X-pass, z = k*4+w.
    float rA[16];
#pragma unroll
    for (int k = 0; k < 16; ++k) {
        int z = k * 4 + w;
        float d = tile[lane * 65 + z];
        int q = 1;
        for (int dd = 1; dd <= 63 && (float)q < d; ++dd) {
            int jl = lane - dd, jr = lane + dd;
            float cl = (jl >= 0) ? tile[jl * 65 + z] : 1e9f;
            float cr = (jr < 64) ? tile[jr * 65 + z] : 1e9f;
            d = fminf(d, fminf(cl, cr) + (float)q);
            q += 2 * dd + 1;
        }
        rA[k] = fminf(d, 1e9f);
    }
    __syncthreads();

    // Phase 3 (lanes = z): refill tile with bg.
#pragma unroll
    for (int k = 0; k < 16; ++k) tile[(k * 4 + w) * 65 + lane] = dB0[k];
    __syncthreads();

    // Phase 4 (lanes = x): bg X-pass.
    float rB[16];
#pragma unroll
    for (int k = 0; k < 16; ++k) {
        int z = k * 4 + w;
        float d = tile[lane * 65 + z];
        int q = 1;
        for (int dd = 1; dd <= 63 && (float)q < d; ++dd) {
            int jl = lane - dd, jr = lane + dd;
            float cl = (jl >= 0) ? tile[jl * 65 + z] : 1e9f;
            float cr = (jr < 64) ? tile[jr * 65 + z] : 1e9f;
            d = fminf(d, fminf(cl, cr) + (float)q);
            q += 2 * dd + 1;
        }
        rB[k] = fminf(d, 1e9f);
    }
    __syncthreads();

    // Phase 5 (lanes = x): pack.
#pragma unroll
    for (int k = 0; k < 16; ++k) {
        int z = k * 4 + w;
        float tot = rA[k] + rB[k];
        int vi = (int)fminf(tot, 32767.f);
        tile16[lane * 65 + z] =
            (unsigned short)(((rB[k] == 0.f) ? 0x8000 : 0) | vi);
    }
    __syncthreads();

    // Phase 6 (lanes = z): coalesced store.
#pragma unroll
    for (int k = 0; k < 16; ++k) {
        int x = k * 4 + w;
        base[x * 4096 + lane] = tile16[x * 65 + lane];
    }
}

// ---------------------------------------------------------------------------
// Kernel 3: fused C-axis DT + HD + softmax stats + CE + pred-has-fg.
// N_c via ballot+popcount (saves 48 shfl); ex[] cached (no double expf).
// ---------------------------------------------------------------------------
__global__ __launch_bounds__(256) void k_chds(const float* __restrict__ in,
                                              const int* __restrict__ tg,
                                              const unsigned short* __restrict__ f,
                                              float* __restrict__ statP,
                                              double* __restrict__ predS,
                                              double* __restrict__ tgtS) {
    __shared__ float part[4][27];
    __shared__ int af;
    if (threadIdx.x == 0) af = 0;
    __syncthreads();

    int blk = blockIdx.x;                       // 0..2047
    int v = blk * 256 + threadIdx.x;
    int b = v >> 18;
    int r = v & (NVOX - 1);
    int t = tg[v];
    int lane = threadIdx.x & 63;
    int wid = threadIdx.x >> 6;

    float xs[8], ex[8];
#pragma unroll
    for (int c = 0; c < 8; ++c) xs[c] = in[(b * 8 + c) * NVOX + r];
    float mx = xs[0];
#pragma unroll
    for (int c = 1; c < 8; ++c) mx = fmaxf(mx, xs[c]);
    float se = 0.f;
#pragma unroll
    for (int c = 0; c < 8; ++c) { ex[c] = expf(xs[c] - mx); se += ex[c]; }
    float inv = 1.f / se;
    float lse = mx + logf(se);
    float xt = xs[0];
#pragma unroll
    for (int c = 1; c < 8; ++c) xt = (t == c) ? xs[c] : xt;

    bool anyP = false;
    float red[17];
    float cnt[8];
#pragma unroll
    for (int c = 0; c < 8; ++c) {
        float p = ex[c] * inv;
        red[c] = p;
        red[8 + c] = (t == c) ? p : 0.f;
        cnt[c] = (float)__popcll(__ballot(t == c));   // wave class count
        anyP = anyP || (xs[c] > 0.5f);
    }
    red[16] = lse - xt;

#pragma unroll
    for (int k = 0; k < 17; ++k) {
        float s = red[k];
        s += __shfl_down(s, 32);
        s += __shfl_down(s, 16);
        s += __shfl_down(s, 8);
        s += __shfl_down(s, 4);
        s += __shfl_down(s, 2);
        s += __shfl_down(s, 1);
        red[k] = s;
    }
    bool wav = __any(anyP);
    if (lane == 0) {
#pragma unroll
        for (int k = 0; k < 8; ++k) part[wid][k] = red[k];
#pragma unroll
        for (int k = 0; k < 8; ++k) part[wid][8 + k] = red[8 + k];
#pragma unroll
        for (int k = 0; k < 8; ++k) part[wid][16 + k] = cnt[k];
        part[wid][24] = red[16];
        if (wav) atomicOr(&af, 1);
    }

    // HD: unpack fg/bg, C-axis min-plus on each, e^2 weighting.
    float e2[8];
#pragma unroll
    for (int c = 0; c < 8; ++c) {
        float e = xs[c] - ((t == c) ? 1.f : 0.f);
        e2[c] = e * e;
    }
    float accP = 0.f, accT = 0.f;
#pragma unroll
    for (int src = 0; src < 2; ++src) {
        float fmA[8], fmB[8];
#pragma unroll
        for (int c = 0; c < 8; ++c) {
            unsigned short p = f[(size_t)src * FMU + (b * 8 + c) * NVOX + r];
            float fv = unpack_val(p);
            bool member = (p & 0x8000) != 0;
            fmA[c] = member ? fv : 0.f;
            fmB[c] = member ? 0.f : fv;
        }
        float am = 0.f;
#pragma unroll
        for (int i = 0; i < 8; ++i) {
            float da = 1e9f, db = 1e9f;
#pragma unroll
            for (int j = 0; j < 8; ++j) {
                float q = (float)((i - j) * (i - j));
                da = fminf(da, fmA[j] + q);
                db = fminf(db, fmB[j] + q);
            }
            am += e2[i] * (da + db);
        }
        if (src) accT += am; else accP += am;
    }
#pragma unroll
    for (int off = 32; off >= 1; off >>= 1) {
        accP += __shfl_down(accP, off);
        accT += __shfl_down(accT, off);
    }
    if (lane == 0) { part[wid][25] = accP; part[wid][26] = accT; }
    __syncthreads();

    int j = blk & 1023;
    if (threadIdx.x < 25)
        statP[(b * 26 + threadIdx.x) * 1024 + j] =
            part[0][threadIdx.x] + part[1][threadIdx.x] +
            part[2][threadIdx.x] + part[3][threadIdx.x];
    if (threadIdx.x == 25)
        statP[(b * 26 + 25) * 1024 + j] = af ? 1.f : 0.f;
    if (threadIdx.x == 26)
        predS[blk] = (double)part[0][25] + (double)part[1][25] +
                     (double)part[2][25] + (double)part[3][25];
    if (threadIdx.x == 27)
        tgtS[blk] = (double)part[0][26] + (double)part[1][26] +
                    (double)part[2][26] + (double)part[3][26];
}

// ---------------------------------------------------------------------------
// Kernel 4: reduce partial rows + assemble scalar loss.
// ---------------------------------------------------------------------------
__global__ __launch_bounds__(256) void k_final3(const float* __restrict__ statP,
                                                const double* __restrict__ predS,
                                                const double* __restrict__ tgtS,
                                                float* __restrict__ out) {
    __shared__ float rs[52];
    __shared__ double rd[4];
    int tid = threadIdx.x;
    int w = tid >> 6;
    int lane = tid & 63;

    for (int row = w; row < 52; row += 4) {
        const float* p = statP + row * 1024;
        float s = 0.f;
#pragma unroll
        for (int k = 0; k < 16; ++k) s += p[k * 64 + lane];
        s += __shfl_down(s, 32);
        s += __shfl_down(s, 16);
        s += __shfl_down(s, 8);
        s += __shfl_down(s, 4);
        s += __shfl_down(s, 2);
        s += __shfl_down(s, 1);
        if (lane == 0) rs[row] = s;
    }
    {
        const double* p = (w < 2) ? (predS + w * 1024) : (tgtS + (w - 2) * 1024);
        double s = 0.0;
#pragma unroll
        for (int k = 0; k < 16; ++k) s += p[k * 64 + lane];
        s += __shfl_down(s, 32);
        s += __shfl_down(s, 16);
        s += __shfl_down(s, 8);
        s += __shfl_down(s, 4);
        s += __shfl_down(s, 2);
        s += __shfl_down(s, 1);
        if (lane == 0) rd[w] = s;
    }
    __syncthreads();

    if (tid == 0) {
        bool fP0 = rs[0 * 26 + 25] > 0.f;
        bool fP1 = rs[1 * 26 + 25] > 0.f;
        double h = (fP0 ? rd[0] : 0.0) + (fP1 ? rd[1] : 0.0) + rd[2] + rd[3];
        float dsum = 0.f;
        for (int c = 1; c < 8; ++c) {
            float sc = 0.f;
            for (int b = 0; b < 2; ++b) {
                float S1 = rs[b * 26 + c];
                float S2 = rs[b * 26 + 8 + c];
                float Nc = rs[b * 26 + 16 + c];
                sc += 2.f * S2 / (2.f * S2 + (S1 - S2) + (Nc - S2) + 1e-5f);
            }
            dsum += sc * 0.5f;
        }
        float dice = 1.f - dsum / 7.f;
        float ce = (rs[0 * 26 + 24] + rs[1 * 26 + 24]) / 524288.f;
        out[0] = dice + ce + (float)(h / 4194304.0);
    }
}

// ===========================================================================
// FALLBACK PATH (small workspace) — legacy float-field kernels (absmax 0.0)
// ===========================================================================
__global__ __launch_bounds__(256, 4) void k_stats(const float* __restrict__ in,
                                                  const int* __restrict__ tg,
                                                  float* __restrict__ accF,
                                                  int* __restrict__ flags) {
    int r = blockIdx.x * 256 + threadIdx.x;
    int lane = threadIdx.x & 63;
    int wid = threadIdx.x >> 6;
    __shared__ float part[4][25];
    __shared__ int af;

    for (int b = 0; b < 2; ++b) {
        int t = tg[b * NVOX + r];
        float xs[8];
#pragma unroll
        for (int c = 0; c < 8; ++c) xs[c] = in[(b * 8 + c) * NVOX + r];
        float mx = xs[0];
#pragma unroll
        for (int c = 1; c < 8; ++c) mx = fmaxf(mx, xs[c]);
        float ex[8];
        float se = 0.f;
#pragma unroll
        for (int c = 0; c < 8; ++c) { ex[c] = expf(xs[c] - mx); se += ex[c]; }
        float inv = 1.f / se;
        float lse = mx + logf(se);
        float xt = xs[0];
#pragma unroll
        for (int c = 1; c < 8; ++c) xt = (t == c) ? xs[c] : xt;
        bool anyP = false;
        float red[25];
#pragma unroll
        for (int c = 0; c < 8; ++c) {
            float p = ex[c] * inv;
            red[c] = p;
            red[8 + c] = (t == c) ? p : 0.f;
            red[16 + c] = (t == c) ? 1.f : 0.f;
            anyP = anyP || (xs[c] > 0.5f);
        }
        red[24] = lse - xt;
#pragma unroll
        for (int k = 0; k < 25; ++k) {
            float s = red[k];
            s += __shfl_down(s, 32);
            s += __shfl_down(s, 16);
            s += __shfl_down(s, 8);
            s += __shfl_down(s, 4);
            s += __shfl_down(s, 2);
            s += __shfl_down(s, 1);
            red[k] = s;
        }
        if (threadIdx.x == 0) af = 0;
        __syncthreads();
        bool wav = __any(anyP);
        if (lane == 0) {
#pragma unroll
            for (int k = 0; k < 25; ++k) part[wid][k] = red[k];
            if (wav) atomicOr(&af, 1);
        }
        __syncthreads();
        if (threadIdx.x < 25) {
            float s = part[0][threadIdx.x] + part[1][threadIdx.x] +
                      part[2][threadIdx.x] + part[3][threadIdx.x];
            atomicAdd(&accF[b * 25 + threadIdx.x], s);
        }
        if (threadIdx.x == 0 && af) atomicOr(&flags[b], 1);
        __syncthreads();
    }
}

template <int M0>
__global__ __launch_bounds__(64) void k_mask_zy(const float* __restrict__ in,
                                                const int* __restrict__ tg,
                                                float* __restrict__ f) {
    __shared__ float tile[64 * 65];
    int blk = blockIdx.x;
    int m = M0 + (blk >> 10);
    int s = blk & 1023;
    int b = s >> 9, c = (s >> 6) & 7, x = s & 63;
    int tid = threadIdx.x;

    if ((m & 1) == 0) {
        const float* src = in + (b * 8 + c) * NVOX + x * 4096;
#pragma unroll 8
        for (int k = 0; k < 64; ++k) {
            bool fg = src[k * 64 + tid] > 0.5f;
            bool hot = (m < 2) ? fg : !fg;
            tile[k * 65 + tid] = hot ? 1e9f : 0.f;
        }
    } else {
        const int* src = tg + b * NVOX + x * 4096;
#pragma unroll 8
        for (int k = 0; k < 64; ++k) {
            bool fg = (src[k * 64 + tid] == c);
            bool hot = (m < 2) ? fg : !fg;
            tile[k * 65 + tid] = hot ? 1e9f : 0.f;
        }
    }
    __syncthreads();
    {
        float* row = &tile[tid * 65];
        float g = 1000.f;
#pragma unroll 8
        for (int z = 0; z < 64; ++z) {
            float v = row[z];
            g = (v == 0.f) ? 0.f : g + 1.f;
            row[z] = g;
        }
        g = 1000.f;
#pragma unroll 8
        for (int z = 63; z >= 0; --z) {
            float gf = row[z];
            g = (gf == 0.f) ? 0.f : g + 1.f;
            float d = fminf(gf, g);
            row[z] = (d > 63.f) ? 1e9f : d * d;
        }
    }
    __syncthreads();
    float* out = f + (size_t)(blk >> 10) * FM + (b * 8 + c) * NVOX + x * 4096;
    for (int i = 0; i < 64; ++i) {
        float d0 = tile[i * 65 + tid];
        float d = d0;
        int Ri = (int)sqrtf(d0) + 1;
        Ri = (Ri > 63) ? 63 : Ri;
        for (int dd = 1; dd <= Ri; ++dd) {
            float q = (float)(dd * dd);
            int jl = i - dd, jr = i + dd;
            float cl = (jl >= 0) ? tile[jl * 65 + tid] : 1e9f;
            float cr = (jr < 64) ? tile[jr * 65 + tid] : 1e9f;
            d = fminf(d, fminf(cl, cr) + q);
        }
        out[i * 64 + tid] = fminf(d, 1e9f);
    }
}

template <int M0>
__global__ __launch_bounds__(128, 4) void k_dtx(float* __restrict__ f) {
    __shared__ float wl[128 * 65];
    int blk = blockIdx.x;
    int mi = blk >> 9;
    int s = blk & 511;
    int plane = s >> 5;
    int y0 = (s & 31) * 2;
    int tid = threadIdx.x;
    float* fb = f + (size_t)mi * FM + plane * NVOX + y0 * 64;

#pragma unroll 8
    for (int j = 0; j < 64; ++j) wl[tid * 65 + j] = fb[j * 4096 + tid];

    float* row = &wl[tid * 65];
    for (int i = 0; i < 64; ++i) {
        float d0 = row[i];
        float d = d0;
        int Ri = (int)sqrtf(d0) + 1;
        Ri = (Ri > 63) ? 63 : Ri;
        for (int dd = 1; dd <= Ri; ++dd) {
            float q = (float)(dd * dd);
            int jl = i - dd, jr = i + dd;
            float cl = (jl >= 0) ? row[jl] : 1e9f;
            float cr = (jr < 64) ? row[jr] : 1e9f;
            d = fminf(d, fminf(cl, cr) + q);
        }
        fb[i * 4096 + tid] = fminf(d, 1e9f);
    }
}

template <int M0, int NM>
__global__ __launch_bounds__(256, 4) void k_cdt_hd(const float* __restrict__ in,
                                                   const int* __restrict__ tg,
                                                   const float* __restrict__ f,
                                                   const int* __restrict__ flags,
                                                   double* __restrict__ hd) {
    int v = blockIdx.x * 256 + threadIdx.x;
    int b = v >> 18;
    int r = v & (NVOX - 1);
    int t = tg[v];

    float e2[8];
#pragma unroll
    for (int c = 0; c < 8; ++c) {
        float e = in[(b * 8 + c) * NVOX + r] - ((t == c) ? 1.f : 0.f);
        e2[c] = e * e;
    }
    float acc = 0.f;
#pragma unroll
    for (int mi = 0; mi < NM; ++mi) {
        int m = M0 + mi;
        float fl = (m & 1) ? 1.f : (flags[b] ? 1.f : 0.f);
        float fm[8];
#pragma unroll
        for (int c = 0; c < 8; ++c)
            fm[c] = f[(size_t)mi * FM + (b * 8 + c) * NVOX + r];
        float am = 0.f;
#pragma unroll
        for (int i = 0; i < 8; ++i) {
            float d = 1e9f;
#pragma unroll
            for (int j = 0; j < 8; ++j)
                d = fminf(d, fm[j] + (float)((i - j) * (i - j)));
            am += e2[i] * d;
        }
        acc += fl * am;
    }
    float ssum = acc;
    ssum += __shfl_down(ssum, 32);
    ssum += __shfl_down(ssum, 16);
    ssum += __shfl_down(ssum, 8);
    ssum += __shfl_down(ssum, 4);
    ssum += __shfl_down(ssum, 2);
    ssum += __shfl_down(ssum, 1);
    __shared__ float part[4];
    int lane = threadIdx.x & 63;
    int wid = threadIdx.x >> 6;
    if (lane == 0) part[wid] = ssum;
    __syncthreads();
    if (threadIdx.x == 0)
        atomicAdd(hd, (double)(part[0] + part[1] + part[2] + part[3]));
}

__global__ void k_final(const float* __restrict__ accF,
                        const double* __restrict__ hd,
                        float* __restrict__ out) {
    float dsum = 0.f;
    for (int c = 1; c < 8; ++c) {
        float sc = 0.f;
        for (int b = 0; b < 2; ++b) {
            float S1 = accF[b * 25 + c];
            float S2 = accF[b * 25 + 8 + c];
            float Nc = accF[b * 25 + 16 + c];
            sc += 2.f * S2 / (2.f * S2 + (S1 - S2) + (Nc - S2) + 1e-5f);
        }
        dsum += sc * 0.5f;
    }
    float dice = 1.f - dsum / 7.f;
    float ce = (accF[24] + accF[25 + 24]) / 524288.f;
    float hdv = (float)(hd[0] / 4194304.0);
    out[0] = dice + ce + hdv;
}

template <int M0, int NM>
static void run_chunk(const float* in, const int* tg, float* f,
                      const int* flags, double* hd, hipStream_t stream) {
    k_mask_zy<M0><<<NM * 1024, 64, 0, stream>>>(in, tg, f);
    k_dtx<M0><<<NM * 512, 128, 0, stream>>>(f);
    k_cdt_hd<M0, NM><<<2048, 256, 0, stream>>>(in, tg, f, flags, hd);
}

// ---------------------------------------------------------------------------
extern "C" void kernel_launch(void* const* d_in, const int* in_sizes, int n_in,
                              void* d_out, int out_size, void* d_ws, size_t ws_size,
                              hipStream_t stream) {
    const float* in = (const float*)d_in[0];
    const int* tg = (const int*)d_in[1];
    float* out = (float*)d_out;

    // fast-path layout: packed u16 fields (2 x 8.4 MB), then partials
    size_t offF = (size_t)2 * FMU * 2;           // 16,777,216 bytes
    size_t need_fast = offF + 16384 + 16384 + 52 * 1024 * 4;

    if (ws_size >= need_fast) {
        unsigned short* fu = (unsigned short*)d_ws;
        double* predS = (double*)((char*)d_ws + offF);
        double* tgtS = (double*)((char*)d_ws + offF + 16384);
        float* statP = (float*)((char*)d_ws + offF + 32768);
        k_zy2<<<2048, 256, 0, stream>>>(in, tg, fu);
        k_xdt<<<2048, 256, 0, stream>>>(fu);
        k_chds<<<2048, 256, 0, stream>>>(in, tg, fu, statP, predS, tgtS);
        k_final3<<<1, 256, 0, stream>>>(statP, predS, tgtS, out);
    } else {
        float* f = (float*)d_ws;
        size_t acc_off = ((ws_size - 256) / 256) * 256;
        char* accB = (char*)d_ws + acc_off;
        double* hd = (double*)accB;
        float* accF = (float*)(accB + 8);
        int* flags = (int*)(accB + 208);
        hipMemsetAsync(accB, 0, 256, stream);
        k_stats<<<1024, 256, 0, stream>>>(in, tg, accF, flags);
        int nm_cap = (int)(acc_off / ((size_t)FM * 4));
        if (nm_cap >= 2) {
            run_chunk<0, 2>(in, tg, f, flags, hd, stream);
            run_chunk<2, 2>(in, tg, f, flags, hd, stream);
        } else if (nm_cap >= 1) {
            run_chunk<0, 1>(in, tg, f, flags, hd, stream);
            run_chunk<1, 1>(in, tg, f, flags, hd, stream);
            run_chunk<2, 1>(in, tg, f, flags, hd, stream);
            run_chunk<3, 1>(in, tg, f, flags, hd, stream);
        }
        k_final<<<1, 1, 0, stream>>>(accF, hd, out);
    }
}